// Round 1
// baseline (7705.228 us; speedup 1.0000x reference)
//
#include <hip/hip_runtime.h>
#include <cmath>

#define B_N 2
#define NFR 8
#define HH 32
#define WW 32
#define LSEQ 8192
#define DIMD 384
#define DI 192
#define DST 16
#define DRK 24
#define HID 1536
#define MR (B_N*LSEQ)   // 16384 rows

// ---------------- workspace layout (floats) ----------------
constexpr size_t SZ_BLD = (size_t)MR * DIMD;   // 6291456
constexpr size_t SZ_BLI = (size_t)MR * DI;     // 3145728
constexpr size_t SZ_DBL = (size_t)MR * 56;     // 917504
constexpr size_t SZ_H   = (size_t)MR * HID;    // 25165824

constexpr size_t OFF_XFLAT = 0;
constexpr size_t OFF_FFLAT = OFF_XFLAT + SZ_BLD;
constexpr size_t OFF_XZ    = OFF_FFLAT + SZ_BLD;
constexpr size_t OFF_XCF   = OFF_XZ + SZ_BLD;
constexpr size_t OFF_XCR   = OFF_XCF + SZ_BLI;
// region1 = [0, 25165824) ; h1 aliases it exactly (dead by fc1 time)
constexpr size_t OFF_H1    = 0;
constexpr size_t OFF_R2    = OFF_XCR + SZ_BLI;      // 25165824
constexpr size_t OFF_DBLF  = OFF_R2;
constexpr size_t OFF_DBLR  = OFF_DBLF + SZ_DBL;
constexpr size_t OFF_DTF   = OFF_DBLR + SZ_DBL;
constexpr size_t OFF_DTR   = OFF_DTF + SZ_BLI;
constexpr size_t OFF_GF    = OFF_DTR + SZ_BLI;
constexpr size_t OFF_GR    = OFF_GF + SZ_BLI;
constexpr size_t OFF_MF    = OFF_GR + SZ_BLI;
constexpr size_t OFF_MR_   = OFF_MF + SZ_BLD;
constexpr size_t OFF_H2    = OFF_R2;                // aliases dbl..m (dead by dwconv time)
constexpr size_t OFF_NORM  = OFF_MR_ + SZ_BLD;      // 52166656  (normed1, later normed2)
constexpr size_t OFF_XM    = OFF_NORM + SZ_BLD;     // 58458112
constexpr size_t OFF_PART  = OFF_XM + SZ_BLD;       // 64749568  (6*16*384)
constexpr size_t OFF_AW    = OFF_PART + 6*16*384;   // 64786432  (2*3*384)
// total ~64788736 floats = ~259.2 MB

__device__ __forceinline__ float siluf(float x){ return x / (1.f + expf(-x)); }
__device__ __forceinline__ float softplusf(float x){ return x > 20.f ? x : log1pf(expf(x)); }
__device__ __forceinline__ float geluf(float x){ return 0.5f * x * (1.f + erff(x * 0.70710678118f)); }

// ============ K1: hilbert gather (x, freq_x) + LayerNorm1 ============
__global__ __launch_bounds__(128)
void k_gather_ln(const float* __restrict__ x, const float* __restrict__ fx,
                 const int* __restrict__ hc, const float* __restrict__ lw,
                 const float* __restrict__ lb, float* __restrict__ x_flat,
                 float* __restrict__ f_flat, float* __restrict__ normed)
{
    int blk = blockIdx.x;            // b*L + l
    int b = blk >> 13, l = blk & (LSEQ-1);
    int p = hc[l];
    int nf = p >> 10, hw = p & 1023;
    const float* xb = x  + ((size_t)(b*NFR+nf)*DIMD)*1024 + hw;
    const float* fb = fx + ((size_t)(b*NFR+nf)*DIMD)*1024 + hw;
    int t = threadIdx.x;
    float v[3]; float s = 0.f, s2 = 0.f;
    #pragma unroll
    for (int i = 0; i < 3; ++i){
        int d = t + i*128;
        float a = xb[(size_t)d*1024];
        v[i] = a; s += a; s2 += a*a;
        x_flat[(size_t)blk*DIMD + d] = a;
        f_flat[(size_t)blk*DIMD + d] = fb[(size_t)d*1024];
    }
    #pragma unroll
    for (int o = 32; o > 0; o >>= 1){ s += __shfl_down(s, o); s2 += __shfl_down(s2, o); }
    __shared__ float sh[4];
    if ((t & 63) == 0){ sh[(t>>6)*2] = s; sh[(t>>6)*2+1] = s2; }
    __syncthreads();
    float S = sh[0] + sh[2], S2 = sh[1] + sh[3];
    float mean = S * (1.f/DIMD);
    float var  = S2 * (1.f/DIMD) - mean*mean;
    float r = rsqrtf(var + 1e-5f);
    #pragma unroll
    for (int i = 0; i < 3; ++i){
        int d = t + i*128;
        normed[(size_t)blk*DIMD + d] = (v[i]-mean)*r*lw[d] + lb[d];
    }
}

// ============ plain row LayerNorm (LN2) ============
__global__ __launch_bounds__(128)
void k_ln(const float* __restrict__ in, const float* __restrict__ lw,
          const float* __restrict__ lb, float* __restrict__ out)
{
    size_t row = blockIdx.x;
    int t = threadIdx.x;
    float v[3]; float s = 0.f, s2 = 0.f;
    #pragma unroll
    for (int i = 0; i < 3; ++i){
        int d = t + i*128;
        float a = in[row*DIMD + d];
        v[i] = a; s += a; s2 += a*a;
    }
    #pragma unroll
    for (int o = 32; o > 0; o >>= 1){ s += __shfl_down(s, o); s2 += __shfl_down(s2, o); }
    __shared__ float sh[4];
    if ((t & 63) == 0){ sh[(t>>6)*2] = s; sh[(t>>6)*2+1] = s2; }
    __syncthreads();
    float S = sh[0] + sh[2], S2 = sh[1] + sh[3];
    float mean = S * (1.f/DIMD);
    float var  = S2 * (1.f/DIMD) - mean*mean;
    float r = rsqrtf(var + 1e-5f);
    #pragma unroll
    for (int i = 0; i < 3; ++i){
        int d = t + i*128;
        out[row*DIMD + d] = (v[i]-mean)*r*lw[d] + lb[d];
    }
}

// ============ GEMM: C[M,N] = A[M,K] @ W[N,K]^T  (+epilogues) ============
// EPI 0: plain store.  EPI 1: +bias.  EPI 2: +bias +add(xm), scatter to d_out via hilbert.
template<int EPI>
__global__ __launch_bounds__(256, 2)
void k_gemm(const float* __restrict__ A, const float* __restrict__ W,
            const float* __restrict__ bias, const float* __restrict__ add,
            const int* __restrict__ hc, float* __restrict__ C, int N, int K)
{
    const int BM = 128, BN = 128, BK = 8;
    __shared__ float As[BK][BM+4];
    __shared__ float Bs[BK][BN+4];
    int tid = threadIdx.x;
    int row0 = blockIdx.x * BM, col0 = blockIdx.y * BN;
    int lr = tid >> 1, lh = (tid & 1) * 4;
    const float* Ag = A + (size_t)(row0+lr)*K + lh;
    const float* Wg = W + (size_t)(col0+lr)*K + lh;
    int ty = tid >> 4, tx = tid & 15;
    float acc[8][8];
    #pragma unroll
    for (int i = 0; i < 8; ++i)
        #pragma unroll
        for (int j = 0; j < 8; ++j) acc[i][j] = 0.f;

    for (int k0 = 0; k0 < K; k0 += BK){
        float4 av = *(const float4*)(Ag + k0);
        float4 wv = *(const float4*)(Wg + k0);
        if (k0) __syncthreads();
        As[lh+0][lr]=av.x; As[lh+1][lr]=av.y; As[lh+2][lr]=av.z; As[lh+3][lr]=av.w;
        Bs[lh+0][lr]=wv.x; Bs[lh+1][lr]=wv.y; Bs[lh+2][lr]=wv.z; Bs[lh+3][lr]=wv.w;
        __syncthreads();
        #pragma unroll
        for (int k = 0; k < BK; ++k){
            float a[8], b[8];
            *(float4*)(a)   = *(const float4*)&As[k][ty*8];
            *(float4*)(a+4) = *(const float4*)&As[k][ty*8+4];
            *(float4*)(b)   = *(const float4*)&Bs[k][tx*8];
            *(float4*)(b+4) = *(const float4*)&Bs[k][tx*8+4];
            #pragma unroll
            for (int i = 0; i < 8; ++i)
                #pragma unroll
                for (int j = 0; j < 8; ++j) acc[i][j] += a[i]*b[j];
        }
    }

    #pragma unroll
    for (int i = 0; i < 8; ++i){
        int row = row0 + ty*8 + i;
        if (EPI == 2){
            int bb = row >> 13, l = row & (LSEQ-1);
            int p = hc[l];
            size_t obase = ((size_t)(bb*NFR + (p>>10))*DIMD)*1024 + (p & 1023);
            #pragma unroll
            for (int j = 0; j < 8; ++j){
                int col = col0 + tx*8 + j;
                float v = acc[i][j] + bias[col] + add[(size_t)row*N + col];
                C[obase + (size_t)col*1024] = v;
            }
        } else {
            float* Crow = C + (size_t)row*N + col0 + tx*8;
            #pragma unroll
            for (int j = 0; j < 8; ++j){
                float v = acc[i][j];
                if (EPI == 1) v += bias[col0 + tx*8 + j];
                Crow[j] = v;
            }
        }
    }
}

// ============ causal + anti-causal depthwise conv over L, + silu ============
__global__ __launch_bounds__(256)
void k_conv(const float* __restrict__ xz, const float* __restrict__ cw,
            const float* __restrict__ cb, float* __restrict__ xcf, float* __restrict__ xcr)
{
    const int TL = 64;
    int b = blockIdx.y;
    int l0 = blockIdx.x * TL;
    __shared__ float sx[TL+6][DI];   // rows hold l0-3 .. l0+TL+2
    for (int idx = threadIdx.x; idx < (TL+6)*DI; idx += 256){
        int r = idx / DI, c = idx % DI;
        int l = l0 + r - 3;
        float v = 0.f;
        if (l >= 0 && l < LSEQ) v = xz[((size_t)b*LSEQ + l)*DIMD + c];
        sx[r][c] = v;
    }
    __syncthreads();
    for (int idx = threadIdx.x; idx < TL*DI; idx += 256){
        int r = idx / DI, c = idx % DI;
        float w0 = cw[c*4+0], w1 = cw[c*4+1], w2 = cw[c*4+2], w3 = cw[c*4+3];
        float bi = cb[c];
        size_t orow = ((size_t)b*LSEQ + l0 + r)*DI + c;
        float af = bi + sx[r][c]*w0 + sx[r+1][c]*w1 + sx[r+2][c]*w2 + sx[r+3][c]*w3;
        xcf[orow] = siluf(af);
        float ar = bi + sx[r+3][c]*w3 + sx[r+4][c]*w2 + sx[r+5][c]*w1 + sx[r+6][c]*w0;
        xcr[orow] = siluf(ar);
    }
}

// ============ dbl = xc @ xproj_w^T  (N=56, K=192) ============
__global__ __launch_bounds__(256)
void k_dbl(const float* __restrict__ xc, const float* __restrict__ xpw, float* __restrict__ dbl)
{
    __shared__ float sw[56*193];
    for (int i = threadIdx.x; i < 56*DI; i += 256){
        int n = i / DI, k = i % DI;
        sw[n*193 + k] = xpw[i];
    }
    __syncthreads();
    int n = threadIdx.x & 63;
    int ri = threadIdx.x >> 6;
    int row0 = blockIdx.x * 16;
    if (n < 56){
        for (int rp = 0; rp < 4; ++rp){
            int row = row0 + rp*4 + ri;
            const float* xr = xc + (size_t)row*DI;
            float acc = 0.f;
            #pragma unroll 8
            for (int k = 0; k < DI; ++k) acc += xr[k] * sw[n*193 + k];
            dbl[(size_t)row*56 + n] = acc;
        }
    }
}

// ============ dt = softplus(dbl[:, :24] @ dt_w^T + dt_b)  (N=192, K=24) ============
__global__ __launch_bounds__(192)
void k_dt(const float* __restrict__ dbl, const float* __restrict__ dtw,
          const float* __restrict__ dtb, float* __restrict__ dt)
{
    int row = blockIdx.x;
    int d = threadIdx.x;
    __shared__ float sd[24];
    if (d < 24) sd[d] = dbl[(size_t)row*56 + d];
    __syncthreads();
    float acc = dtb[d];
    #pragma unroll
    for (int r = 0; r < DRK; ++r) acc += sd[r] * dtw[d*DRK + r];
    dt[(size_t)row*DI + d] = softplusf(acc);
}

// ============ selective scan (fwd: dir=0, rev: dir=1) fused with gating ============
// g[b,l,d] = (y[b,l,d] + Dp[d]*xc[b,l,d]) * silu(z[b,l,d])
__global__ __launch_bounds__(256)
void k_scan(const float* __restrict__ dt, const float* __restrict__ dbl,
            const float* __restrict__ xc, const float* __restrict__ xz,
            const float* __restrict__ A_log, const float* __restrict__ Dp,
            float* __restrict__ g, int dir)
{
    int d0 = blockIdx.x * 16;
    int b  = blockIdx.y;
    int tid = threadIdx.x;
    int s = tid & 15, di = tid >> 4;
    int d = d0 + di;
    float A2  = -expf(A_log[d*DST + s]) * 1.44269504f;   // for exp2
    float Dpd = Dp[d];
    float h = 0.f;
    __shared__ float sdt[16][16], sxv[16][16], szv[16][16], sB[16][16], sC[16][16];
    int r = tid >> 4, cix = tid & 15;   // loader mapping: r = step-in-chunk
    for (int chunk = 0; chunk < LSEQ/16; ++chunk){
        __syncthreads();
        int lld = (dir == 0) ? (chunk*16 + r) : (LSEQ-1 - (chunk*16 + r));
        size_t rowbl = (size_t)b*LSEQ + lld;
        sdt[r][cix] = dt[rowbl*DI + d0 + cix];
        sxv[r][cix] = xc[rowbl*DI + d0 + cix];
        szv[r][cix] = xz[rowbl*DIMD + DI + d0 + cix];
        sB[r][cix]  = dbl[rowbl*56 + 24 + cix];
        sC[r][cix]  = dbl[rowbl*56 + 40 + cix];
        __syncthreads();
        #pragma unroll 4
        for (int j = 0; j < 16; ++j){
            float dtv = sdt[j][di];
            float xv  = sxv[j][di];
            float da  = exp2f(dtv * A2);
            float db  = dtv * sB[j][s] * xv;
            h = da*h + db;
            float yc = h * sC[j][s];
            yc += __shfl_xor(yc, 8);
            yc += __shfl_xor(yc, 4);
            yc += __shfl_xor(yc, 2);
            yc += __shfl_xor(yc, 1);
            if (s == 0){
                float zv = szv[j][di];
                int lw = (dir == 0) ? (chunk*16 + j) : (LSEQ-1 - (chunk*16 + j));
                g[((size_t)b*LSEQ + lw)*DI + d] = (yc + Dpd*xv) * siluf(zv);
            }
        }
    }
}

// ============ pooled partial sums over L (for SSA) ============
__global__ __launch_bounds__(256)
void k_pool(const float* __restrict__ m_f, const float* __restrict__ m_r,
            const float* __restrict__ f_flat, float* __restrict__ partial)
{
    int bt = blockIdx.x;      // b*3 + t
    int sl = blockIdx.y;      // 16 slices of 512
    int b = bt / 3, t = bt % 3;
    const float* src = (t == 0) ? m_f : (t == 1) ? m_r : f_flat;
    src += (size_t)b*LSEQ*DIMD;
    for (int d = threadIdx.x; d < DIMD; d += 256){
        float sum = 0.f;
        for (int l = sl*512; l < (sl+1)*512; ++l) sum += src[(size_t)l*DIMD + d];
        partial[((size_t)bt*16 + sl)*DIMD + d] = sum;
    }
}

// ============ SSA attention weights: softmax over t ============
__global__ __launch_bounds__(384)
void k_ssa(const float* __restrict__ partial, const float* __restrict__ ssaw,
           float* __restrict__ aw)
{
    int b = blockIdx.x;
    int d = threadIdx.x;
    float pooled[3];
    #pragma unroll
    for (int t = 0; t < 3; ++t){
        float sum = 0.f;
        #pragma unroll
        for (int sl = 0; sl < 16; ++sl) sum += partial[((size_t)(b*3+t)*16 + sl)*DIMD + d];
        pooled[t] = sum * (1.f/LSEQ);
    }
    float wv[3];
    #pragma unroll
    for (int t = 0; t < 3; ++t)
        wv[t] = pooled[0]*ssaw[d*9 + t*3 + 0] + pooled[1]*ssaw[d*9 + t*3 + 1] + pooled[2]*ssaw[d*9 + t*3 + 2];
    float mx = fmaxf(wv[0], fmaxf(wv[1], wv[2]));
    float e0 = expf(wv[0]-mx), e1 = expf(wv[1]-mx), e2 = expf(wv[2]-mx);
    float inv = 1.f / (e0+e1+e2);
    aw[(size_t)(b*3+0)*DIMD + d] = e0*inv;
    aw[(size_t)(b*3+1)*DIMD + d] = e1*inv;
    aw[(size_t)(b*3+2)*DIMD + d] = e2*inv;
}

// ============ xm = x_flat + sum_t aw[t]*seq_t ============
__global__ __launch_bounds__(256)
void k_xm(const float* __restrict__ x_flat, const float* __restrict__ m_f,
          const float* __restrict__ m_r, const float* __restrict__ f_flat,
          const float* __restrict__ aw, float* __restrict__ xm)
{
    size_t idx = (size_t)blockIdx.x*256 + threadIdx.x;
    int d = (int)(idx % DIMD);
    size_t row = idx / DIMD;
    int b = (int)(row >> 13);
    float a0 = aw[(size_t)(b*3+0)*DIMD + d];
    float a1 = aw[(size_t)(b*3+1)*DIMD + d];
    float a2 = aw[(size_t)(b*3+2)*DIMD + d];
    xm[idx] = x_flat[idx] + a0*m_f[idx] + a1*m_r[idx] + a2*f_flat[idx];
}

// ============ depthwise 3x3x3 conv over (NF,H,W) + bias + exact GELU ============
__global__ __launch_bounds__(256)
void k_dwconv(const float* __restrict__ h1, const float* __restrict__ dww,
              const float* __restrict__ dwb, float* __restrict__ h2)
{
    int c = blockIdx.x*256 + threadIdx.x;
    int h = blockIdx.y;
    int bnf = blockIdx.z; int b = bnf >> 3, nf = bnf & 7;
    float wt[27];
    #pragma unroll
    for (int i = 0; i < 27; ++i) wt[i] = dww[(size_t)c*27 + i];
    float bias = dwb[c];
    bool nfok[3], hok[3];
    #pragma unroll
    for (int dd = 0; dd < 3; ++dd){
        nfok[dd] = (nf+dd-1) >= 0 && (nf+dd-1) < NFR;
        hok[dd]  = (h+dd-1)  >= 0 && (h+dd-1)  < HH;
    }
    const float* base = h1 + (size_t)b*LSEQ*HID + c;
    float win[3][3][3];
    #pragma unroll
    for (int dn = 0; dn < 3; ++dn)
        #pragma unroll
        for (int dh = 0; dh < 3; ++dh){
            bool ok = nfok[dn] && hok[dh];
            size_t rb = ((size_t)(nf+dn-1)*1024 + (size_t)(h+dh-1)*32);
            win[dn][dh][0] = 0.f;
            win[dn][dh][1] = ok ? base[(rb + 0)*HID] : 0.f;
            win[dn][dh][2] = ok ? base[(rb + 1)*HID] : 0.f;
        }
    for (int xw = 0; xw < WW; ++xw){
        float acc = bias;
        #pragma unroll
        for (int dn = 0; dn < 3; ++dn)
            #pragma unroll
            for (int dh = 0; dh < 3; ++dh)
                #pragma unroll
                for (int dw = 0; dw < 3; ++dw)
                    acc += win[dn][dh][dw] * wt[dn*9 + dh*3 + dw];
        h2[((size_t)b*LSEQ + nf*1024 + h*32 + xw)*HID + c] = geluf(acc);
        int wn = xw + 2;
        #pragma unroll
        for (int dn = 0; dn < 3; ++dn)
            #pragma unroll
            for (int dh = 0; dh < 3; ++dh){
                win[dn][dh][0] = win[dn][dh][1];
                win[dn][dh][1] = win[dn][dh][2];
                bool ok = (wn < WW) && nfok[dn] && hok[dh];
                size_t rb = ((size_t)(nf+dn-1)*1024 + (size_t)(h+dh-1)*32);
                win[dn][dh][2] = ok ? base[(rb + wn)*HID] : 0.f;
            }
    }
}

// ================================================================
extern "C" void kernel_launch(void* const* d_in, const int* in_sizes, int n_in,
                              void* d_out, int out_size, void* d_ws, size_t ws_size,
                              hipStream_t stream)
{
    const float* x     = (const float*)d_in[0];
    const float* fx    = (const float*)d_in[1];
    const int*   hc    = (const int*)  d_in[2];
    const float* ln1w  = (const float*)d_in[3];
    const float* ln1b  = (const float*)d_in[4];
    const float* inpw  = (const float*)d_in[5];
    const float* convw = (const float*)d_in[6];
    const float* convb = (const float*)d_in[7];
    const float* xpw   = (const float*)d_in[8];
    const float* dtw   = (const float*)d_in[9];
    const float* dtb   = (const float*)d_in[10];
    const float* alog  = (const float*)d_in[11];
    const float* dp    = (const float*)d_in[12];
    const float* outpw = (const float*)d_in[13];
    const float* ssaw  = (const float*)d_in[14];
    const float* ln2w  = (const float*)d_in[15];
    const float* ln2b  = (const float*)d_in[16];
    const float* fc1w  = (const float*)d_in[17];
    const float* fc1b  = (const float*)d_in[18];
    const float* dww   = (const float*)d_in[19];
    const float* dwb   = (const float*)d_in[20];
    const float* fc2w  = (const float*)d_in[21];
    const float* fc2b  = (const float*)d_in[22];

    float* ws = (float*)d_ws;
    float* x_flat = ws + OFF_XFLAT;
    float* f_flat = ws + OFF_FFLAT;
    float* xz     = ws + OFF_XZ;
    float* xc_f   = ws + OFF_XCF;
    float* xc_r   = ws + OFF_XCR;
    float* dbl_f  = ws + OFF_DBLF;
    float* dbl_r  = ws + OFF_DBLR;
    float* dt_f   = ws + OFF_DTF;
    float* dt_r   = ws + OFF_DTR;
    float* g_f    = ws + OFF_GF;
    float* g_r    = ws + OFF_GR;
    float* m_f    = ws + OFF_MF;
    float* m_r    = ws + OFF_MR_;
    float* h1     = ws + OFF_H1;
    float* h2     = ws + OFF_H2;
    float* normed = ws + OFF_NORM;
    float* xm     = ws + OFF_XM;
    float* part   = ws + OFF_PART;
    float* aw     = ws + OFF_AW;
    float* outp   = (float*)d_out;

    // 1. gather + LN1
    k_gather_ln<<<MR, 128, 0, stream>>>(x, fx, hc, ln1w, ln1b, x_flat, f_flat, normed);
    // 2. in_proj (shared by fwd & rev)
    k_gemm<0><<<dim3(128,3), 256, 0, stream>>>(normed, inpw, nullptr, nullptr, nullptr, xz, DIMD, DIMD);
    // 3. causal/anti-causal depthwise conv + silu
    k_conv<<<dim3(LSEQ/64, B_N), 256, 0, stream>>>(xz, convw, convb, xc_f, xc_r);
    // 4. x-proj (dbl = [dt_raw, B, C])
    k_dbl<<<MR/16, 256, 0, stream>>>(xc_f, xpw, dbl_f);
    k_dbl<<<MR/16, 256, 0, stream>>>(xc_r, xpw, dbl_r);
    // 5. dt projection + softplus
    k_dt<<<MR, 192, 0, stream>>>(dbl_f, dtw, dtb, dt_f);
    k_dt<<<MR, 192, 0, stream>>>(dbl_r, dtw, dtb, dt_r);
    // 6. selective scans (fused gating epilogue)
    k_scan<<<dim3(12, B_N), 256, 0, stream>>>(dt_f, dbl_f, xc_f, xz, alog, dp, g_f, 0);
    k_scan<<<dim3(12, B_N), 256, 0, stream>>>(dt_r, dbl_r, xc_r, xz, alog, dp, g_r, 1);
    // 7. out_proj
    k_gemm<0><<<dim3(128,3), 256, 0, stream>>>(g_f, outpw, nullptr, nullptr, nullptr, m_f, DIMD, DI);
    k_gemm<0><<<dim3(128,3), 256, 0, stream>>>(g_r, outpw, nullptr, nullptr, nullptr, m_r, DIMD, DI);
    // 8. SSA
    k_pool<<<dim3(6,16), 256, 0, stream>>>(m_f, m_r, f_flat, part);
    k_ssa<<<B_N, 384, 0, stream>>>(part, ssaw, aw);
    k_xm<<<(unsigned)(SZ_BLD/256), 256, 0, stream>>>(x_flat, m_f, m_r, f_flat, aw, xm);
    // 9. MLP
    k_ln<<<MR, 128, 0, stream>>>(xm, ln2w, ln2b, normed);
    k_gemm<1><<<dim3(128,12), 256, 0, stream>>>(normed, fc1w, fc1b, nullptr, nullptr, h1, HID, DIMD);
    k_dwconv<<<dim3(6,32,16), 256, 0, stream>>>(h1, dww, dwb, h2);
    // 10. fc2 + residual + hilbert scatter to output
    k_gemm<2><<<dim3(128,3), 256, 0, stream>>>(h2, fc2w, fc2b, xm, hc, outp, DIMD, HID);
}

// Round 2
// 1759.693 us; speedup vs baseline: 4.3787x; 4.3787x over previous
//
#include <hip/hip_runtime.h>
#include <cmath>

#define B_N 2
#define NFR 8
#define HH 32
#define WW 32
#define LSEQ 8192
#define DIMD 384
#define DI 192
#define DST 16
#define DRK 24
#define HID 1536
#define MR (B_N*LSEQ)   // 16384 rows

#define NCH 64          // scan chunks
#define CL  (LSEQ/NCH)  // 128 steps per chunk

// ---------------- workspace layout (floats) ----------------
constexpr size_t SZ_BLD = (size_t)MR * DIMD;   // 6291456
constexpr size_t SZ_BLI = (size_t)MR * DI;     // 3145728
constexpr size_t SZ_DBL = (size_t)MR * 56;     // 917504

constexpr size_t OFF_XFLAT = 0;
constexpr size_t OFF_FFLAT = OFF_XFLAT + SZ_BLD;
constexpr size_t OFF_XZ    = OFF_FFLAT + SZ_BLD;
constexpr size_t OFF_XCF   = OFF_XZ + SZ_BLD;
constexpr size_t OFF_XCR   = OFF_XCF + SZ_BLI;
// region1 = [0, 25165824) ; h1 aliases it exactly (dead by fc1 time)
constexpr size_t OFF_H1    = 0;
constexpr size_t OFF_R2    = OFF_XCR + SZ_BLI;      // 25165824
constexpr size_t OFF_DBLF  = OFF_R2;
constexpr size_t OFF_DBLR  = OFF_DBLF + SZ_DBL;
constexpr size_t OFF_DTF   = OFF_DBLR + SZ_DBL;
constexpr size_t OFF_DTR   = OFF_DTF + SZ_BLI;
constexpr size_t OFF_GF    = OFF_DTR + SZ_BLI;
constexpr size_t OFF_GR    = OFF_GF + SZ_BLI;
constexpr size_t OFF_MF    = OFF_GR + SZ_BLI;
constexpr size_t OFF_MR_   = OFF_MF + SZ_BLD;
constexpr size_t OFF_H2    = OFF_R2;                // aliases dbl..m (dead by dwconv time)
constexpr size_t OFF_NORM  = OFF_MR_ + SZ_BLD;      // normed1 / later normed2
constexpr size_t OFF_XM    = OFF_NORM + SZ_BLD;
constexpr size_t OFF_PART  = OFF_XM + SZ_BLD;
constexpr size_t OFF_AW    = OFF_PART + 6*16*384;
// scan chunk summaries alias the (dead-at-scan-time) normed region:
constexpr size_t SZ_CH   = (size_t)2*B_N*12*NCH*256;      // 786432
constexpr size_t OFF_CA  = OFF_NORM;
constexpr size_t OFF_CB  = OFF_CA + SZ_CH;
constexpr size_t OFF_CHS = OFF_CB + SZ_CH;                // < OFF_NORM + SZ_BLD

__device__ __forceinline__ float siluf(float x){ return x / (1.f + expf(-x)); }
__device__ __forceinline__ float softplusf(float x){ return x > 20.f ? x : log1pf(expf(x)); }
__device__ __forceinline__ float geluf(float x){ return 0.5f * x * (1.f + erff(x * 0.70710678118f)); }

// ============ K1: hilbert gather (x, freq_x) + LayerNorm1 ============
__global__ __launch_bounds__(128)
void k_gather_ln(const float* __restrict__ x, const float* __restrict__ fx,
                 const int* __restrict__ hc, const float* __restrict__ lw,
                 const float* __restrict__ lb, float* __restrict__ x_flat,
                 float* __restrict__ f_flat, float* __restrict__ normed)
{
    int blk = blockIdx.x;            // b*L + l
    int b = blk >> 13, l = blk & (LSEQ-1);
    int p = hc[l];
    int nf = p >> 10, hw = p & 1023;
    const float* xb = x  + ((size_t)(b*NFR+nf)*DIMD)*1024 + hw;
    const float* fb = fx + ((size_t)(b*NFR+nf)*DIMD)*1024 + hw;
    int t = threadIdx.x;
    float v[3]; float s = 0.f, s2 = 0.f;
    #pragma unroll
    for (int i = 0; i < 3; ++i){
        int d = t + i*128;
        float a = xb[(size_t)d*1024];
        v[i] = a; s += a; s2 += a*a;
        x_flat[(size_t)blk*DIMD + d] = a;
        f_flat[(size_t)blk*DIMD + d] = fb[(size_t)d*1024];
    }
    #pragma unroll
    for (int o = 32; o > 0; o >>= 1){ s += __shfl_down(s, o); s2 += __shfl_down(s2, o); }
    __shared__ float sh[4];
    if ((t & 63) == 0){ sh[(t>>6)*2] = s; sh[(t>>6)*2+1] = s2; }
    __syncthreads();
    float S = sh[0] + sh[2], S2 = sh[1] + sh[3];
    float mean = S * (1.f/DIMD);
    float var  = S2 * (1.f/DIMD) - mean*mean;
    float r = rsqrtf(var + 1e-5f);
    #pragma unroll
    for (int i = 0; i < 3; ++i){
        int d = t + i*128;
        normed[(size_t)blk*DIMD + d] = (v[i]-mean)*r*lw[d] + lb[d];
    }
}

// ============ plain row LayerNorm (LN2) ============
__global__ __launch_bounds__(128)
void k_ln(const float* __restrict__ in, const float* __restrict__ lw,
          const float* __restrict__ lb, float* __restrict__ out)
{
    size_t row = blockIdx.x;
    int t = threadIdx.x;
    float v[3]; float s = 0.f, s2 = 0.f;
    #pragma unroll
    for (int i = 0; i < 3; ++i){
        int d = t + i*128;
        float a = in[row*DIMD + d];
        v[i] = a; s += a; s2 += a*a;
    }
    #pragma unroll
    for (int o = 32; o > 0; o >>= 1){ s += __shfl_down(s, o); s2 += __shfl_down(s2, o); }
    __shared__ float sh[4];
    if ((t & 63) == 0){ sh[(t>>6)*2] = s; sh[(t>>6)*2+1] = s2; }
    __syncthreads();
    float S = sh[0] + sh[2], S2 = sh[1] + sh[3];
    float mean = S * (1.f/DIMD);
    float var  = S2 * (1.f/DIMD) - mean*mean;
    float r = rsqrtf(var + 1e-5f);
    #pragma unroll
    for (int i = 0; i < 3; ++i){
        int d = t + i*128;
        out[row*DIMD + d] = (v[i]-mean)*r*lw[d] + lb[d];
    }
}

// ============ GEMM: C[M,N] = A[M,K] @ W[N,K]^T  (+epilogues) ============
// EPI 0: plain store.  EPI 1: +bias.  EPI 2: +bias +add(xm), scatter to d_out via hilbert.
template<int EPI>
__global__ __launch_bounds__(256, 2)
void k_gemm(const float* __restrict__ A, const float* __restrict__ W,
            const float* __restrict__ bias, const float* __restrict__ add,
            const int* __restrict__ hc, float* __restrict__ C, int N, int K)
{
    const int BM = 128, BN = 128, BK = 8;
    __shared__ float As[BK][BM+4];
    __shared__ float Bs[BK][BN+4];
    int tid = threadIdx.x;
    int row0 = blockIdx.x * BM, col0 = blockIdx.y * BN;
    int lr = tid >> 1, lh = (tid & 1) * 4;
    const float* Ag = A + (size_t)(row0+lr)*K + lh;
    const float* Wg = W + (size_t)(col0+lr)*K + lh;
    int ty = tid >> 4, tx = tid & 15;
    float acc[8][8];
    #pragma unroll
    for (int i = 0; i < 8; ++i)
        #pragma unroll
        for (int j = 0; j < 8; ++j) acc[i][j] = 0.f;

    for (int k0 = 0; k0 < K; k0 += BK){
        float4 av = *(const float4*)(Ag + k0);
        float4 wv = *(const float4*)(Wg + k0);
        if (k0) __syncthreads();
        As[lh+0][lr]=av.x; As[lh+1][lr]=av.y; As[lh+2][lr]=av.z; As[lh+3][lr]=av.w;
        Bs[lh+0][lr]=wv.x; Bs[lh+1][lr]=wv.y; Bs[lh+2][lr]=wv.z; Bs[lh+3][lr]=wv.w;
        __syncthreads();
        #pragma unroll
        for (int k = 0; k < BK; ++k){
            float a[8], b[8];
            *(float4*)(a)   = *(const float4*)&As[k][ty*8];
            *(float4*)(a+4) = *(const float4*)&As[k][ty*8+4];
            *(float4*)(b)   = *(const float4*)&Bs[k][tx*8];
            *(float4*)(b+4) = *(const float4*)&Bs[k][tx*8+4];
            #pragma unroll
            for (int i = 0; i < 8; ++i)
                #pragma unroll
                for (int j = 0; j < 8; ++j) acc[i][j] += a[i]*b[j];
        }
    }

    #pragma unroll
    for (int i = 0; i < 8; ++i){
        int row = row0 + ty*8 + i;
        if (EPI == 2){
            int bb = row >> 13, l = row & (LSEQ-1);
            int p = hc[l];
            size_t obase = ((size_t)(bb*NFR + (p>>10))*DIMD)*1024 + (p & 1023);
            #pragma unroll
            for (int j = 0; j < 8; ++j){
                int col = col0 + tx*8 + j;
                float v = acc[i][j] + bias[col] + add[(size_t)row*N + col];
                C[obase + (size_t)col*1024] = v;
            }
        } else {
            float* Crow = C + (size_t)row*N + col0 + tx*8;
            #pragma unroll
            for (int j = 0; j < 8; ++j){
                float v = acc[i][j];
                if (EPI == 1) v += bias[col0 + tx*8 + j];
                Crow[j] = v;
            }
        }
    }
}

// ============ causal + anti-causal depthwise conv over L, + silu ============
__global__ __launch_bounds__(256)
void k_conv(const float* __restrict__ xz, const float* __restrict__ cw,
            const float* __restrict__ cb, float* __restrict__ xcf, float* __restrict__ xcr)
{
    const int TL = 64;
    int b = blockIdx.y;
    int l0 = blockIdx.x * TL;
    __shared__ float sx[TL+6][DI];   // rows hold l0-3 .. l0+TL+2
    for (int idx = threadIdx.x; idx < (TL+6)*DI; idx += 256){
        int r = idx / DI, c = idx % DI;
        int l = l0 + r - 3;
        float v = 0.f;
        if (l >= 0 && l < LSEQ) v = xz[((size_t)b*LSEQ + l)*DIMD + c];
        sx[r][c] = v;
    }
    __syncthreads();
    for (int idx = threadIdx.x; idx < TL*DI; idx += 256){
        int r = idx / DI, c = idx % DI;
        float w0 = cw[c*4+0], w1 = cw[c*4+1], w2 = cw[c*4+2], w3 = cw[c*4+3];
        float bi = cb[c];
        size_t orow = ((size_t)b*LSEQ + l0 + r)*DI + c;
        float af = bi + sx[r][c]*w0 + sx[r+1][c]*w1 + sx[r+2][c]*w2 + sx[r+3][c]*w3;
        xcf[orow] = siluf(af);
        float ar = bi + sx[r+3][c]*w3 + sx[r+4][c]*w2 + sx[r+5][c]*w1 + sx[r+6][c]*w0;
        xcr[orow] = siluf(ar);
    }
}

// ============ dbl = xc @ xproj_w^T  (N=56, K=192) ============
__global__ __launch_bounds__(256)
void k_dbl(const float* __restrict__ xc, const float* __restrict__ xpw, float* __restrict__ dbl)
{
    __shared__ float sw[56*193];
    for (int i = threadIdx.x; i < 56*DI; i += 256){
        int n = i / DI, k = i % DI;
        sw[n*193 + k] = xpw[i];
    }
    __syncthreads();
    int n = threadIdx.x & 63;
    int ri = threadIdx.x >> 6;
    int row0 = blockIdx.x * 16;
    if (n < 56){
        for (int rp = 0; rp < 4; ++rp){
            int row = row0 + rp*4 + ri;
            const float* xr = xc + (size_t)row*DI;
            float acc = 0.f;
            #pragma unroll 8
            for (int k = 0; k < DI; ++k) acc += xr[k] * sw[n*193 + k];
            dbl[(size_t)row*56 + n] = acc;
        }
    }
}

// ============ dt = softplus(dbl[:, :24] @ dt_w^T + dt_b)  (N=192, K=24) ============
__global__ __launch_bounds__(192)
void k_dt(const float* __restrict__ dbl, const float* __restrict__ dtw,
          const float* __restrict__ dtb, float* __restrict__ dt)
{
    int row = blockIdx.x;
    int d = threadIdx.x;
    __shared__ float sd[24];
    if (d < 24) sd[d] = dbl[(size_t)row*56 + d];
    __syncthreads();
    float acc = dtb[d];
    #pragma unroll
    for (int r = 0; r < DRK; ++r) acc += sd[r] * dtw[d*DRK + r];
    dt[(size_t)row*DI + d] = softplusf(acc);
}

// ============ chunked selective scan ============
// p1: per-chunk composed (A = prod da, B = local scan from h=0)
__global__ __launch_bounds__(256)
void k_scan_p1(const float* __restrict__ dt_f, const float* __restrict__ dt_r,
               const float* __restrict__ dbl_f, const float* __restrict__ dbl_r,
               const float* __restrict__ xc_f, const float* __restrict__ xc_r,
               const float* __restrict__ A_log,
               float* __restrict__ CA, float* __restrict__ CB)
{
    int dir = blockIdx.z;
    int b   = blockIdx.y;
    int dg  = blockIdx.x >> 6;       // 0..11
    int ch  = blockIdx.x & (NCH-1);  // 0..63
    const float* dt  = dir ? dt_r  : dt_f;
    const float* dbl = dir ? dbl_r : dbl_f;
    const float* xc  = dir ? xc_r  : xc_f;
    int d0 = dg*16;
    int tid = threadIdx.x;
    int s = tid & 15, di = tid >> 4;
    int d = d0 + di;
    float A2 = -expf(A_log[d*DST + s]) * 1.44269504f;
    float hA = 1.f, hB = 0.f;
    __shared__ float sdt[16][16], sxv[16][16], sB[16][16];
    int r = tid >> 4, cix = tid & 15;
    for (int sub = 0; sub < CL/16; ++sub){
        __syncthreads();
        int lidx = ch*CL + sub*16 + r;
        int lld = dir ? (LSEQ-1-lidx) : lidx;
        size_t rowbl = (size_t)b*LSEQ + lld;
        sdt[r][cix] = dt[rowbl*DI + d0 + cix];
        sxv[r][cix] = xc[rowbl*DI + d0 + cix];
        sB[r][cix]  = dbl[rowbl*56 + 24 + cix];
        __syncthreads();
        #pragma unroll
        for (int j = 0; j < 16; ++j){
            float dtv = sdt[j][di];
            float da  = exp2f(dtv * A2);
            float db  = dtv * sB[j][s] * sxv[j][di];
            hA *= da;
            hB = da*hB + db;
        }
    }
    size_t o = ((((size_t)dir*B_N + b)*12 + dg)*NCH + ch)*256 + tid;
    CA[o] = hA; CB[o] = hB;
}

// p2: sequential combine over chunk summaries -> incoming state per chunk
__global__ __launch_bounds__(256)
void k_scan_p2(const float* __restrict__ CA, const float* __restrict__ CB,
               float* __restrict__ CH)
{
    int dir = blockIdx.z, b = blockIdx.y, dg = blockIdx.x;
    int tid = threadIdx.x;
    size_t base = ((((size_t)dir*B_N + b)*12 + dg)*NCH)*256 + tid;
    float h = 0.f;
    for (int c = 0; c < NCH; ++c){
        size_t o = base + (size_t)c*256;
        CH[o] = h;
        h = CA[o]*h + CB[o];
    }
}

// p3: rescan from h_in, compute y, gate, write g
__global__ __launch_bounds__(256)
void k_scan_p3(const float* __restrict__ dt_f, const float* __restrict__ dt_r,
               const float* __restrict__ dbl_f, const float* __restrict__ dbl_r,
               const float* __restrict__ xc_f, const float* __restrict__ xc_r,
               const float* __restrict__ xz, const float* __restrict__ A_log,
               const float* __restrict__ Dp, const float* __restrict__ CH,
               float* __restrict__ g_f, float* __restrict__ g_r)
{
    int dir = blockIdx.z;
    int b   = blockIdx.y;
    int dg  = blockIdx.x >> 6;
    int ch  = blockIdx.x & (NCH-1);
    const float* dt  = dir ? dt_r  : dt_f;
    const float* dbl = dir ? dbl_r : dbl_f;
    const float* xc  = dir ? xc_r  : xc_f;
    float* g = dir ? g_r : g_f;
    int d0 = dg*16;
    int tid = threadIdx.x;
    int s = tid & 15, di = tid >> 4;
    int d = d0 + di;
    float A2  = -expf(A_log[d*DST + s]) * 1.44269504f;
    float Dpd = Dp[d];
    float h = CH[((((size_t)dir*B_N + b)*12 + dg)*NCH + ch)*256 + tid];
    __shared__ float sdt[16][16], sxv[16][16], szv[16][16], sB[16][16], sC[16][16];
    int r = tid >> 4, cix = tid & 15;
    for (int sub = 0; sub < CL/16; ++sub){
        __syncthreads();
        int lidx = ch*CL + sub*16 + r;
        int lld = dir ? (LSEQ-1-lidx) : lidx;
        size_t rowbl = (size_t)b*LSEQ + lld;
        sdt[r][cix] = dt[rowbl*DI + d0 + cix];
        sxv[r][cix] = xc[rowbl*DI + d0 + cix];
        szv[r][cix] = xz[rowbl*DIMD + DI + d0 + cix];
        sB[r][cix]  = dbl[rowbl*56 + 24 + cix];
        sC[r][cix]  = dbl[rowbl*56 + 40 + cix];
        __syncthreads();
        #pragma unroll 4
        for (int j = 0; j < 16; ++j){
            float dtv = sdt[j][di];
            float xv  = sxv[j][di];
            float da  = exp2f(dtv * A2);
            float db  = dtv * sB[j][s] * xv;
            h = da*h + db;
            float yc = h * sC[j][s];
            yc += __shfl_xor(yc, 8);
            yc += __shfl_xor(yc, 4);
            yc += __shfl_xor(yc, 2);
            yc += __shfl_xor(yc, 1);
            if (s == 0){
                float zv = szv[j][di];
                int lidxj = ch*CL + sub*16 + j;
                int lw = dir ? (LSEQ-1-lidxj) : lidxj;
                g[((size_t)b*LSEQ + lw)*DI + d] = (yc + Dpd*xv) * siluf(zv);
            }
        }
    }
}

// ============ pooled partial sums over L (for SSA) ============
__global__ __launch_bounds__(256)
void k_pool(const float* __restrict__ m_f, const float* __restrict__ m_r,
            const float* __restrict__ f_flat, float* __restrict__ partial)
{
    int bt = blockIdx.x;      // b*3 + t
    int sl = blockIdx.y;      // 16 slices of 512
    int b = bt / 3, t = bt % 3;
    const float* src = (t == 0) ? m_f : (t == 1) ? m_r : f_flat;
    src += (size_t)b*LSEQ*DIMD;
    for (int d = threadIdx.x; d < DIMD; d += 256){
        float sum = 0.f;
        for (int l = sl*512; l < (sl+1)*512; ++l) sum += src[(size_t)l*DIMD + d];
        partial[((size_t)bt*16 + sl)*DIMD + d] = sum;
    }
}

// ============ SSA attention weights: softmax over t ============
__global__ __launch_bounds__(384)
void k_ssa(const float* __restrict__ partial, const float* __restrict__ ssaw,
           float* __restrict__ aw)
{
    int b = blockIdx.x;
    int d = threadIdx.x;
    float pooled[3];
    #pragma unroll
    for (int t = 0; t < 3; ++t){
        float sum = 0.f;
        #pragma unroll
        for (int sl = 0; sl < 16; ++sl) sum += partial[((size_t)(b*3+t)*16 + sl)*DIMD + d];
        pooled[t] = sum * (1.f/LSEQ);
    }
    float wv[3];
    #pragma unroll
    for (int t = 0; t < 3; ++t)
        wv[t] = pooled[0]*ssaw[d*9 + t*3 + 0] + pooled[1]*ssaw[d*9 + t*3 + 1] + pooled[2]*ssaw[d*9 + t*3 + 2];
    float mx = fmaxf(wv[0], fmaxf(wv[1], wv[2]));
    float e0 = expf(wv[0]-mx), e1 = expf(wv[1]-mx), e2 = expf(wv[2]-mx);
    float inv = 1.f / (e0+e1+e2);
    aw[(size_t)(b*3+0)*DIMD + d] = e0*inv;
    aw[(size_t)(b*3+1)*DIMD + d] = e1*inv;
    aw[(size_t)(b*3+2)*DIMD + d] = e2*inv;
}

// ============ xm = x_flat + sum_t aw[t]*seq_t ============
__global__ __launch_bounds__(256)
void k_xm(const float* __restrict__ x_flat, const float* __restrict__ m_f,
          const float* __restrict__ m_r, const float* __restrict__ f_flat,
          const float* __restrict__ aw, float* __restrict__ xm)
{
    size_t idx = (size_t)blockIdx.x*256 + threadIdx.x;
    int d = (int)(idx % DIMD);
    size_t row = idx / DIMD;
    int b = (int)(row >> 13);
    float a0 = aw[(size_t)(b*3+0)*DIMD + d];
    float a1 = aw[(size_t)(b*3+1)*DIMD + d];
    float a2 = aw[(size_t)(b*3+2)*DIMD + d];
    xm[idx] = x_flat[idx] + a0*m_f[idx] + a1*m_r[idx] + a2*f_flat[idx];
}

// ============ depthwise 3x3x3 conv over (NF,H,W) + bias + exact GELU ============
__global__ __launch_bounds__(256)
void k_dwconv(const float* __restrict__ h1, const float* __restrict__ dww,
              const float* __restrict__ dwb, float* __restrict__ h2)
{
    int c = blockIdx.x*256 + threadIdx.x;
    int h = blockIdx.y;
    int bnf = blockIdx.z; int b = bnf >> 3, nf = bnf & 7;
    float wt[27];
    #pragma unroll
    for (int i = 0; i < 27; ++i) wt[i] = dww[(size_t)c*27 + i];
    float bias = dwb[c];
    bool nfok[3], hok[3];
    #pragma unroll
    for (int dd = 0; dd < 3; ++dd){
        nfok[dd] = (nf+dd-1) >= 0 && (nf+dd-1) < NFR;
        hok[dd]  = (h+dd-1)  >= 0 && (h+dd-1)  < HH;
    }
    const float* base = h1 + (size_t)b*LSEQ*HID + c;
    float win[3][3][3];
    #pragma unroll
    for (int dn = 0; dn < 3; ++dn)
        #pragma unroll
        for (int dh = 0; dh < 3; ++dh){
            bool ok = nfok[dn] && hok[dh];
            size_t rb = ((size_t)(nf+dn-1)*1024 + (size_t)(h+dh-1)*32);
            win[dn][dh][0] = 0.f;
            win[dn][dh][1] = ok ? base[(rb + 0)*HID] : 0.f;
            win[dn][dh][2] = ok ? base[(rb + 1)*HID] : 0.f;
        }
    for (int xw = 0; xw < WW; ++xw){
        float acc = bias;
        #pragma unroll
        for (int dn = 0; dn < 3; ++dn)
            #pragma unroll
            for (int dh = 0; dh < 3; ++dh)
                #pragma unroll
                for (int dw = 0; dw < 3; ++dw)
                    acc += win[dn][dh][dw] * wt[dn*9 + dh*3 + dw];
        h2[((size_t)b*LSEQ + nf*1024 + h*32 + xw)*HID + c] = geluf(acc);
        int wn = xw + 2;
        #pragma unroll
        for (int dn = 0; dn < 3; ++dn)
            #pragma unroll
            for (int dh = 0; dh < 3; ++dh){
                win[dn][dh][0] = win[dn][dh][1];
                win[dn][dh][1] = win[dn][dh][2];
                bool ok = (wn < WW) && nfok[dn] && hok[dh];
                size_t rb = ((size_t)(nf+dn-1)*1024 + (size_t)(h+dh-1)*32);
                win[dn][dh][2] = ok ? base[(rb + wn)*HID] : 0.f;
            }
    }
}

// ================================================================
extern "C" void kernel_launch(void* const* d_in, const int* in_sizes, int n_in,
                              void* d_out, int out_size, void* d_ws, size_t ws_size,
                              hipStream_t stream)
{
    const float* x     = (const float*)d_in[0];
    const float* fx    = (const float*)d_in[1];
    const int*   hc    = (const int*)  d_in[2];
    const float* ln1w  = (const float*)d_in[3];
    const float* ln1b  = (const float*)d_in[4];
    const float* inpw  = (const float*)d_in[5];
    const float* convw = (const float*)d_in[6];
    const float* convb = (const float*)d_in[7];
    const float* xpw   = (const float*)d_in[8];
    const float* dtw   = (const float*)d_in[9];
    const float* dtb   = (const float*)d_in[10];
    const float* alog  = (const float*)d_in[11];
    const float* dp    = (const float*)d_in[12];
    const float* outpw = (const float*)d_in[13];
    const float* ssaw  = (const float*)d_in[14];
    const float* ln2w  = (const float*)d_in[15];
    const float* ln2b  = (const float*)d_in[16];
    const float* fc1w  = (const float*)d_in[17];
    const float* fc1b  = (const float*)d_in[18];
    const float* dww   = (const float*)d_in[19];
    const float* dwb   = (const float*)d_in[20];
    const float* fc2w  = (const float*)d_in[21];
    const float* fc2b  = (const float*)d_in[22];

    float* ws = (float*)d_ws;
    float* x_flat = ws + OFF_XFLAT;
    float* f_flat = ws + OFF_FFLAT;
    float* xz     = ws + OFF_XZ;
    float* xc_f   = ws + OFF_XCF;
    float* xc_r   = ws + OFF_XCR;
    float* dbl_f  = ws + OFF_DBLF;
    float* dbl_r  = ws + OFF_DBLR;
    float* dt_f   = ws + OFF_DTF;
    float* dt_r   = ws + OFF_DTR;
    float* g_f    = ws + OFF_GF;
    float* g_r    = ws + OFF_GR;
    float* m_f    = ws + OFF_MF;
    float* m_r    = ws + OFF_MR_;
    float* h1     = ws + OFF_H1;
    float* h2     = ws + OFF_H2;
    float* normed = ws + OFF_NORM;
    float* xm     = ws + OFF_XM;
    float* part   = ws + OFF_PART;
    float* aw     = ws + OFF_AW;
    float* cA     = ws + OFF_CA;
    float* cB     = ws + OFF_CB;
    float* cH     = ws + OFF_CHS;
    float* outp   = (float*)d_out;

    // 1. gather + LN1
    k_gather_ln<<<MR, 128, 0, stream>>>(x, fx, hc, ln1w, ln1b, x_flat, f_flat, normed);
    // 2. in_proj (shared by fwd & rev)
    k_gemm<0><<<dim3(128,3), 256, 0, stream>>>(normed, inpw, nullptr, nullptr, nullptr, xz, DIMD, DIMD);
    // 3. causal/anti-causal depthwise conv + silu
    k_conv<<<dim3(LSEQ/64, B_N), 256, 0, stream>>>(xz, convw, convb, xc_f, xc_r);
    // 4. x-proj (dbl = [dt_raw, B, C])
    k_dbl<<<MR/16, 256, 0, stream>>>(xc_f, xpw, dbl_f);
    k_dbl<<<MR/16, 256, 0, stream>>>(xc_r, xpw, dbl_r);
    // 5. dt projection + softplus
    k_dt<<<MR, 192, 0, stream>>>(dbl_f, dtw, dtb, dt_f);
    k_dt<<<MR, 192, 0, stream>>>(dbl_r, dtw, dtb, dt_r);
    // 6. chunked selective scans (both dirs in one launch; normed is dead here)
    k_scan_p1<<<dim3(12*NCH, B_N, 2), 256, 0, stream>>>(dt_f, dt_r, dbl_f, dbl_r, xc_f, xc_r, alog, cA, cB);
    k_scan_p2<<<dim3(12, B_N, 2), 256, 0, stream>>>(cA, cB, cH);
    k_scan_p3<<<dim3(12*NCH, B_N, 2), 256, 0, stream>>>(dt_f, dt_r, dbl_f, dbl_r, xc_f, xc_r, xz, alog, dp, cH, g_f, g_r);
    // 7. out_proj
    k_gemm<0><<<dim3(128,3), 256, 0, stream>>>(g_f, outpw, nullptr, nullptr, nullptr, m_f, DIMD, DI);
    k_gemm<0><<<dim3(128,3), 256, 0, stream>>>(g_r, outpw, nullptr, nullptr, nullptr, m_r, DIMD, DI);
    // 8. SSA
    k_pool<<<dim3(6,16), 256, 0, stream>>>(m_f, m_r, f_flat, part);
    k_ssa<<<B_N, 384, 0, stream>>>(part, ssaw, aw);
    k_xm<<<(unsigned)(SZ_BLD/256), 256, 0, stream>>>(x_flat, m_f, m_r, f_flat, aw, xm);
    // 9. MLP
    k_ln<<<MR, 128, 0, stream>>>(xm, ln2w, ln2b, normed);
    k_gemm<1><<<dim3(128,12), 256, 0, stream>>>(normed, fc1w, fc1b, nullptr, nullptr, h1, HID, DIMD);
    k_dwconv<<<dim3(6,32,16), 256, 0, stream>>>(h1, dww, dwb, h2);
    // 10. fc2 + residual + hilbert scatter to output
    k_gemm<2><<<dim3(128,3), 256, 0, stream>>>(h2, fc2w, fc2b, xm, hc, outp, DIMD, HID);
}

// Round 3
// 1187.712 us; speedup vs baseline: 6.4875x; 1.4816x over previous
//
#include <hip/hip_runtime.h>
#include <cmath>

#define B_N 2
#define NFR 8
#define HH 32
#define WW 32
#define LSEQ 8192
#define DIMD 384
#define DI 192
#define DST 16
#define DRK 24
#define HID 1536
#define MR (B_N*LSEQ)   // 16384 rows

#define NCH 64          // scan chunks
#define CL  (LSEQ/NCH)  // 128 steps per chunk

typedef __attribute__((ext_vector_type(8))) short  bf16x8;
typedef __attribute__((ext_vector_type(4))) float  f32x4;
typedef __attribute__((ext_vector_type(8))) unsigned short u16x8;

// ---------------- workspace layout (floats) ----------------
constexpr size_t SZ_BLD = (size_t)MR * DIMD;   // 6291456
constexpr size_t SZ_BLI = (size_t)MR * DI;     // 3145728
constexpr size_t SZ_DBL = (size_t)MR * 56;     // 917504

constexpr size_t OFF_XFLAT = 0;
constexpr size_t OFF_FFLAT = OFF_XFLAT + SZ_BLD;
constexpr size_t OFF_XZ    = OFF_FFLAT + SZ_BLD;
constexpr size_t OFF_XCF   = OFF_XZ + SZ_BLD;
constexpr size_t OFF_XCR   = OFF_XCF + SZ_BLI;
// region1 = [0, 25165824) ; h1 aliases it exactly (dead by fc1 time)
constexpr size_t OFF_H1    = 0;
constexpr size_t OFF_R2    = OFF_XCR + SZ_BLI;      // 25165824
constexpr size_t OFF_DBLF  = OFF_R2;
constexpr size_t OFF_DBLR  = OFF_DBLF + SZ_DBL;
constexpr size_t OFF_DTF   = OFF_DBLR + SZ_DBL;
constexpr size_t OFF_DTR   = OFF_DTF + SZ_BLI;
constexpr size_t OFF_GF    = OFF_DTR + SZ_BLI;      // bf16 g_f (as shorts)
constexpr size_t OFF_GR    = OFF_GF + SZ_BLI;       // bf16 g_r
constexpr size_t OFF_MF    = OFF_GR + SZ_BLI;
constexpr size_t OFF_MR_   = OFF_MF + SZ_BLD;
constexpr size_t OFF_H2    = OFF_R2;                // bf16 h2 (as shorts; dbl..m dead by dwconv)
constexpr size_t OFF_NORM  = OFF_MR_ + SZ_BLD;      // bf16 normed1 / normed2 (as shorts)
constexpr size_t OFF_XM    = OFF_NORM + SZ_BLD;
constexpr size_t OFF_PART  = OFF_XM + SZ_BLD;
constexpr size_t OFF_AW    = OFF_PART + 6*16*384;
// scan chunk summaries alias the (dead-at-scan-time) normed region:
constexpr size_t SZ_CH   = (size_t)2*B_N*12*NCH*256;      // 786432
constexpr size_t OFF_CA  = OFF_NORM;
constexpr size_t OFF_CB  = OFF_CA + SZ_CH;
constexpr size_t OFF_CHS = OFF_CB + SZ_CH;                // < OFF_NORM + SZ_BLD

__device__ __forceinline__ float siluf(float x){ return x / (1.f + expf(-x)); }
__device__ __forceinline__ float softplusf(float x){ return x > 20.f ? x : log1pf(expf(x)); }
__device__ __forceinline__ float geluf(float x){ return 0.5f * x * (1.f + erff(x * 0.70710678118f)); }
__device__ __forceinline__ unsigned short f2bf(float f){
    union { float f; unsigned int u; } v; v.f = f;
    unsigned int u = v.u + 0x7fffu + ((v.u >> 16) & 1u);
    return (unsigned short)(u >> 16);
}

#if __has_builtin(__builtin_amdgcn_global_load_lds)
#define HAVE_GLL 1
__device__ __forceinline__ void gload16(const void* g, void* l){
    __builtin_amdgcn_global_load_lds((const __attribute__((address_space(1))) void*)g,
                                     (__attribute__((address_space(3))) void*)l, 16, 0, 0);
}
#else
#define HAVE_GLL 0
#endif

// ============ K1: hilbert gather (x, freq_x) + LayerNorm1 (bf16 out) ============
__global__ __launch_bounds__(128)
void k_gather_ln(const float* __restrict__ x, const float* __restrict__ fx,
                 const int* __restrict__ hc, const float* __restrict__ lw,
                 const float* __restrict__ lb, float* __restrict__ x_flat,
                 float* __restrict__ f_flat, unsigned short* __restrict__ normed)
{
    int blk = blockIdx.x;            // b*L + l
    int b = blk >> 13, l = blk & (LSEQ-1);
    int p = hc[l];
    int nf = p >> 10, hw = p & 1023;
    const float* xb = x  + ((size_t)(b*NFR+nf)*DIMD)*1024 + hw;
    const float* fb = fx + ((size_t)(b*NFR+nf)*DIMD)*1024 + hw;
    int t = threadIdx.x;
    float v[3]; float s = 0.f, s2 = 0.f;
    #pragma unroll
    for (int i = 0; i < 3; ++i){
        int d = t + i*128;
        float a = xb[(size_t)d*1024];
        v[i] = a; s += a; s2 += a*a;
        x_flat[(size_t)blk*DIMD + d] = a;
        f_flat[(size_t)blk*DIMD + d] = fb[(size_t)d*1024];
    }
    #pragma unroll
    for (int o = 32; o > 0; o >>= 1){ s += __shfl_down(s, o); s2 += __shfl_down(s2, o); }
    __shared__ float sh[4];
    if ((t & 63) == 0){ sh[(t>>6)*2] = s; sh[(t>>6)*2+1] = s2; }
    __syncthreads();
    float S = sh[0] + sh[2], S2 = sh[1] + sh[3];
    float mean = S * (1.f/DIMD);
    float var  = S2 * (1.f/DIMD) - mean*mean;
    float r = rsqrtf(var + 1e-5f);
    #pragma unroll
    for (int i = 0; i < 3; ++i){
        int d = t + i*128;
        normed[(size_t)blk*DIMD + d] = f2bf((v[i]-mean)*r*lw[d] + lb[d]);
    }
}

// ============ plain row LayerNorm (LN2), bf16 out ============
__global__ __launch_bounds__(128)
void k_ln(const float* __restrict__ in, const float* __restrict__ lw,
          const float* __restrict__ lb, unsigned short* __restrict__ out)
{
    size_t row = blockIdx.x;
    int t = threadIdx.x;
    float v[3]; float s = 0.f, s2 = 0.f;
    #pragma unroll
    for (int i = 0; i < 3; ++i){
        int d = t + i*128;
        float a = in[row*DIMD + d];
        v[i] = a; s += a; s2 += a*a;
    }
    #pragma unroll
    for (int o = 32; o > 0; o >>= 1){ s += __shfl_down(s, o); s2 += __shfl_down(s2, o); }
    __shared__ float sh[4];
    if ((t & 63) == 0){ sh[(t>>6)*2] = s; sh[(t>>6)*2+1] = s2; }
    __syncthreads();
    float S = sh[0] + sh[2], S2 = sh[1] + sh[3];
    float mean = S * (1.f/DIMD);
    float var  = S2 * (1.f/DIMD) - mean*mean;
    float r = rsqrtf(var + 1e-5f);
    #pragma unroll
    for (int i = 0; i < 3; ++i){
        int d = t + i*128;
        out[row*DIMD + d] = f2bf((v[i]-mean)*r*lw[d] + lb[d]);
    }
}

// ============ bf16 MFMA GEMM: C[M,N] = A[M,K](bf16) @ W[N,K](f32->bf16)^T ============
// EPI 0: plain f32 store.  EPI 1: +bias.  EPI 2: +bias +add(xm), scatter via hilbert.
template<int EPI>
__global__ __launch_bounds__(256, 2)
void k_bgemm(const unsigned short* __restrict__ A, const float* __restrict__ Wf,
             const float* __restrict__ bias, const float* __restrict__ add,
             const int* __restrict__ hc, float* __restrict__ C, int N, int K)
{
    __shared__ unsigned short As[128*32];   // linear [128 rows][32 k]
    __shared__ unsigned short Bs[128*48];   // padded [128 rows][48] (32 used)
    int tid  = threadIdx.x;
    int wid  = tid >> 6, lane = tid & 63;
    int row0 = blockIdx.x * 128, col0 = blockIdx.y * 128;
    int wr = wid >> 1, wc = wid & 1;        // wave tile: 64x64
    int lr = lane & 15, lg = lane >> 4;

    f32x4 acc[4][4];
    #pragma unroll
    for (int m = 0; m < 4; ++m)
        #pragma unroll
        for (int n = 0; n < 4; ++n) acc[m][n] = (f32x4){0.f,0.f,0.f,0.f};

    // A staging geometry: slot byte s = wid*2048 + i*1024 + lane*16
    int sA0 = wid*2048 + lane*16;
    int rA0 = sA0 >> 6, kA0 = (sA0 & 63) >> 1;
    int sA1 = sA0 + 1024;
    int rA1 = sA1 >> 6, kA1 = (sA1 & 63) >> 1;
    const unsigned short* Ag0 = A + (size_t)(row0 + rA0)*K + kA0;
    const unsigned short* Ag1 = A + (size_t)(row0 + rA1)*K + kA1;
    // B staging: thread -> (n = tid>>1, kpart = (tid&1)*16)
    int bn = tid >> 1, bkp = (tid & 1) * 16;
    const float* Wg = Wf + (size_t)(col0 + bn)*K + bkp;

    const unsigned short* Ab = &As[(wr*64 + lr)*32 + lg*8];
    const unsigned short* Bb = &Bs[(wc*64 + lr)*48 + lg*8];
    unsigned short* Bw = &Bs[bn*48 + bkp];

    for (int k0 = 0; k0 < K; k0 += 32){
        if (k0) __syncthreads();
#if HAVE_GLL
        gload16(Ag0, (char*)As + wid*2048);
        gload16(Ag1, (char*)As + wid*2048 + 1024);
#else
        *(u16x8*)((char*)As + sA0) = *(const u16x8*)Ag0;
        *(u16x8*)((char*)As + sA1) = *(const u16x8*)Ag1;
#endif
        Ag0 += 32; Ag1 += 32;
        {
            float4 f0 = *(const float4*)(Wg+0);
            float4 f1 = *(const float4*)(Wg+4);
            float4 f2 = *(const float4*)(Wg+8);
            float4 f3 = *(const float4*)(Wg+12);
            Wg += 32;
            u16x8 p0, p1;
            p0[0]=f2bf(f0.x); p0[1]=f2bf(f0.y); p0[2]=f2bf(f0.z); p0[3]=f2bf(f0.w);
            p0[4]=f2bf(f1.x); p0[5]=f2bf(f1.y); p0[6]=f2bf(f1.z); p0[7]=f2bf(f1.w);
            p1[0]=f2bf(f2.x); p1[1]=f2bf(f2.y); p1[2]=f2bf(f2.z); p1[3]=f2bf(f2.w);
            p1[4]=f2bf(f3.x); p1[5]=f2bf(f3.y); p1[6]=f2bf(f3.z); p1[7]=f2bf(f3.w);
            *(u16x8*)(Bw)     = p0;
            *(u16x8*)(Bw + 8) = p1;
        }
        __syncthreads();
        bf16x8 af[4], bfr[4];
        #pragma unroll
        for (int m = 0; m < 4; ++m) af[m]  = *(const bf16x8*)(Ab + m*512);   // m*16*32
        #pragma unroll
        for (int n = 0; n < 4; ++n) bfr[n] = *(const bf16x8*)(Bb + n*768);   // n*16*48
        #pragma unroll
        for (int m = 0; m < 4; ++m)
            #pragma unroll
            for (int n = 0; n < 4; ++n)
                acc[m][n] = __builtin_amdgcn_mfma_f32_16x16x32_bf16(af[m], bfr[n], acc[m][n], 0, 0, 0);
    }

    // epilogue: D row = (lane>>4)*4 + r, col = lane&15 within each 16x16 frag
    #pragma unroll
    for (int m = 0; m < 4; ++m){
        #pragma unroll
        for (int r = 0; r < 4; ++r){
            int row = row0 + wr*64 + m*16 + lg*4 + r;
            if (EPI == 2){
                int bb = row >> 13, l = row & (LSEQ-1);
                int p = hc[l];
                size_t obase = ((size_t)(bb*NFR + (p>>10))*DIMD)*1024 + (p & 1023);
                #pragma unroll
                for (int n = 0; n < 4; ++n){
                    int col = col0 + wc*64 + n*16 + lr;
                    float v = acc[m][n][r] + bias[col] + add[(size_t)row*N + col];
                    C[obase + (size_t)col*1024] = v;
                }
            } else {
                #pragma unroll
                for (int n = 0; n < 4; ++n){
                    int col = col0 + wc*64 + n*16 + lr;
                    float v = acc[m][n][r];
                    if (EPI == 1) v += bias[col];
                    C[(size_t)row*N + col] = v;
                }
            }
        }
    }
}

// ============ causal + anti-causal depthwise conv over L, + silu ============
__global__ __launch_bounds__(256)
void k_conv(const float* __restrict__ xz, const float* __restrict__ cw,
            const float* __restrict__ cb, float* __restrict__ xcf, float* __restrict__ xcr)
{
    const int TL = 64;
    int b = blockIdx.y;
    int l0 = blockIdx.x * TL;
    __shared__ float sx[TL+6][DI];   // rows hold l0-3 .. l0+TL+2
    for (int idx = threadIdx.x; idx < (TL+6)*DI; idx += 256){
        int r = idx / DI, c = idx % DI;
        int l = l0 + r - 3;
        float v = 0.f;
        if (l >= 0 && l < LSEQ) v = xz[((size_t)b*LSEQ + l)*DIMD + c];
        sx[r][c] = v;
    }
    __syncthreads();
    for (int idx = threadIdx.x; idx < TL*DI; idx += 256){
        int r = idx / DI, c = idx % DI;
        float w0 = cw[c*4+0], w1 = cw[c*4+1], w2 = cw[c*4+2], w3 = cw[c*4+3];
        float bi = cb[c];
        size_t orow = ((size_t)b*LSEQ + l0 + r)*DI + c;
        float af = bi + sx[r][c]*w0 + sx[r+1][c]*w1 + sx[r+2][c]*w2 + sx[r+3][c]*w3;
        xcf[orow] = siluf(af);
        float ar = bi + sx[r+3][c]*w3 + sx[r+4][c]*w2 + sx[r+5][c]*w1 + sx[r+6][c]*w0;
        xcr[orow] = siluf(ar);
    }
}

// ============ dbl = xc @ xproj_w^T  (N=56, K=192) ============
__global__ __launch_bounds__(256)
void k_dbl(const float* __restrict__ xc, const float* __restrict__ xpw, float* __restrict__ dbl)
{
    __shared__ float sw[56*193];
    for (int i = threadIdx.x; i < 56*DI; i += 256){
        int n = i / DI, k = i % DI;
        sw[n*193 + k] = xpw[i];
    }
    __syncthreads();
    int n = threadIdx.x & 63;
    int ri = threadIdx.x >> 6;
    int row0 = blockIdx.x * 16;
    if (n < 56){
        for (int rp = 0; rp < 4; ++rp){
            int row = row0 + rp*4 + ri;
            const float* xr = xc + (size_t)row*DI;
            float acc = 0.f;
            #pragma unroll 8
            for (int k = 0; k < DI; ++k) acc += xr[k] * sw[n*193 + k];
            dbl[(size_t)row*56 + n] = acc;
        }
    }
}

// ============ dt = softplus(dbl[:, :24] @ dt_w^T + dt_b)  (N=192, K=24) ============
__global__ __launch_bounds__(192)
void k_dt(const float* __restrict__ dbl, const float* __restrict__ dtw,
          const float* __restrict__ dtb, float* __restrict__ dt)
{
    int row = blockIdx.x;
    int d = threadIdx.x;
    __shared__ float sd[24];
    if (d < 24) sd[d] = dbl[(size_t)row*56 + d];
    __syncthreads();
    float acc = dtb[d];
    #pragma unroll
    for (int r = 0; r < DRK; ++r) acc += sd[r] * dtw[d*DRK + r];
    dt[(size_t)row*DI + d] = softplusf(acc);
}

// ============ chunked selective scan ============
// p1: per-chunk composed (A = prod da, B = local scan from h=0)
__global__ __launch_bounds__(256)
void k_scan_p1(const float* __restrict__ dt_f, const float* __restrict__ dt_r,
               const float* __restrict__ dbl_f, const float* __restrict__ dbl_r,
               const float* __restrict__ xc_f, const float* __restrict__ xc_r,
               const float* __restrict__ A_log,
               float* __restrict__ CA, float* __restrict__ CB)
{
    int dir = blockIdx.z;
    int b   = blockIdx.y;
    int dg  = blockIdx.x >> 6;       // 0..11
    int ch  = blockIdx.x & (NCH-1);  // 0..63
    const float* dt  = dir ? dt_r  : dt_f;
    const float* dbl = dir ? dbl_r : dbl_f;
    const float* xc  = dir ? xc_r  : xc_f;
    int d0 = dg*16;
    int tid = threadIdx.x;
    int s = tid & 15, di = tid >> 4;
    int d = d0 + di;
    float A2 = -expf(A_log[d*DST + s]) * 1.44269504f;
    float hA = 1.f, hB = 0.f;
    __shared__ float sdt[16][16], sxv[16][16], sB[16][16];
    int r = tid >> 4, cix = tid & 15;
    for (int sub = 0; sub < CL/16; ++sub){
        __syncthreads();
        int lidx = ch*CL + sub*16 + r;
        int lld = dir ? (LSEQ-1-lidx) : lidx;
        size_t rowbl = (size_t)b*LSEQ + lld;
        sdt[r][cix] = dt[rowbl*DI + d0 + cix];
        sxv[r][cix] = xc[rowbl*DI + d0 + cix];
        sB[r][cix]  = dbl[rowbl*56 + 24 + cix];
        __syncthreads();
        #pragma unroll
        for (int j = 0; j < 16; ++j){
            float dtv = sdt[j][di];
            float da  = exp2f(dtv * A2);
            float db  = dtv * sB[j][s] * sxv[j][di];
            hA *= da;
            hB = da*hB + db;
        }
    }
    size_t o = ((((size_t)dir*B_N + b)*12 + dg)*NCH + ch)*256 + tid;
    CA[o] = hA; CB[o] = hB;
}

// p2: sequential combine over chunk summaries -> incoming state per chunk
__global__ __launch_bounds__(256)
void k_scan_p2(const float* __restrict__ CA, const float* __restrict__ CB,
               float* __restrict__ CH)
{
    int dir = blockIdx.z, b = blockIdx.y, dg = blockIdx.x;
    int tid = threadIdx.x;
    size_t base = ((((size_t)dir*B_N + b)*12 + dg)*NCH)*256 + tid;
    float h = 0.f;
    for (int c = 0; c < NCH; ++c){
        size_t o = base + (size_t)c*256;
        CH[o] = h;
        h = CA[o]*h + CB[o];
    }
}

// p3: rescan from h_in, compute y, gate, write g (bf16)
__global__ __launch_bounds__(256)
void k_scan_p3(const float* __restrict__ dt_f, const float* __restrict__ dt_r,
               const float* __restrict__ dbl_f, const float* __restrict__ dbl_r,
               const float* __restrict__ xc_f, const float* __restrict__ xc_r,
               const float* __restrict__ xz, const float* __restrict__ A_log,
               const float* __restrict__ Dp, const float* __restrict__ CH,
               unsigned short* __restrict__ g_f, unsigned short* __restrict__ g_r)
{
    int dir = blockIdx.z;
    int b   = blockIdx.y;
    int dg  = blockIdx.x >> 6;
    int ch  = blockIdx.x & (NCH-1);
    const float* dt  = dir ? dt_r  : dt_f;
    const float* dbl = dir ? dbl_r : dbl_f;
    const float* xc  = dir ? xc_r  : xc_f;
    unsigned short* g = dir ? g_r : g_f;
    int d0 = dg*16;
    int tid = threadIdx.x;
    int s = tid & 15, di = tid >> 4;
    int d = d0 + di;
    float A2  = -expf(A_log[d*DST + s]) * 1.44269504f;
    float Dpd = Dp[d];
    float h = CH[((((size_t)dir*B_N + b)*12 + dg)*NCH + ch)*256 + tid];
    __shared__ float sdt[16][16], sxv[16][16], szv[16][16], sB[16][16], sC[16][16];
    int r = tid >> 4, cix = tid & 15;
    for (int sub = 0; sub < CL/16; ++sub){
        __syncthreads();
        int lidx = ch*CL + sub*16 + r;
        int lld = dir ? (LSEQ-1-lidx) : lidx;
        size_t rowbl = (size_t)b*LSEQ + lld;
        sdt[r][cix] = dt[rowbl*DI + d0 + cix];
        sxv[r][cix] = xc[rowbl*DI + d0 + cix];
        szv[r][cix] = xz[rowbl*DIMD + DI + d0 + cix];
        sB[r][cix]  = dbl[rowbl*56 + 24 + cix];
        sC[r][cix]  = dbl[rowbl*56 + 40 + cix];
        __syncthreads();
        #pragma unroll 4
        for (int j = 0; j < 16; ++j){
            float dtv = sdt[j][di];
            float xv  = sxv[j][di];
            float da  = exp2f(dtv * A2);
            float db  = dtv * sB[j][s] * xv;
            h = da*h + db;
            float yc = h * sC[j][s];
            yc += __shfl_xor(yc, 8);
            yc += __shfl_xor(yc, 4);
            yc += __shfl_xor(yc, 2);
            yc += __shfl_xor(yc, 1);
            if (s == 0){
                float zv = szv[j][di];
                int lidxj = ch*CL + sub*16 + j;
                int lw = dir ? (LSEQ-1-lidxj) : lidxj;
                g[((size_t)b*LSEQ + lw)*DI + d] = f2bf((yc + Dpd*xv) * siluf(zv));
            }
        }
    }
}

// ============ pooled partial sums over L (for SSA) ============
__global__ __launch_bounds__(256)
void k_pool(const float* __restrict__ m_f, const float* __restrict__ m_r,
            const float* __restrict__ f_flat, float* __restrict__ partial)
{
    int bt = blockIdx.x;      // b*3 + t
    int sl = blockIdx.y;      // 16 slices of 512
    int b = bt / 3, t = bt % 3;
    const float* src = (t == 0) ? m_f : (t == 1) ? m_r : f_flat;
    src += (size_t)b*LSEQ*DIMD;
    for (int d = threadIdx.x; d < DIMD; d += 256){
        float sum = 0.f;
        for (int l = sl*512; l < (sl+1)*512; ++l) sum += src[(size_t)l*DIMD + d];
        partial[((size_t)bt*16 + sl)*DIMD + d] = sum;
    }
}

// ============ SSA attention weights: softmax over t ============
__global__ __launch_bounds__(384)
void k_ssa(const float* __restrict__ partial, const float* __restrict__ ssaw,
           float* __restrict__ aw)
{
    int b = blockIdx.x;
    int d = threadIdx.x;
    float pooled[3];
    #pragma unroll
    for (int t = 0; t < 3; ++t){
        float sum = 0.f;
        #pragma unroll
        for (int sl = 0; sl < 16; ++sl) sum += partial[((size_t)(b*3+t)*16 + sl)*DIMD + d];
        pooled[t] = sum * (1.f/LSEQ);
    }
    float wv[3];
    #pragma unroll
    for (int t = 0; t < 3; ++t)
        wv[t] = pooled[0]*ssaw[d*9 + t*3 + 0] + pooled[1]*ssaw[d*9 + t*3 + 1] + pooled[2]*ssaw[d*9 + t*3 + 2];
    float mx = fmaxf(wv[0], fmaxf(wv[1], wv[2]));
    float e0 = expf(wv[0]-mx), e1 = expf(wv[1]-mx), e2 = expf(wv[2]-mx);
    float inv = 1.f / (e0+e1+e2);
    aw[(size_t)(b*3+0)*DIMD + d] = e0*inv;
    aw[(size_t)(b*3+1)*DIMD + d] = e1*inv;
    aw[(size_t)(b*3+2)*DIMD + d] = e2*inv;
}

// ============ xm = x_flat + sum_t aw[t]*seq_t ============
__global__ __launch_bounds__(256)
void k_xm(const float* __restrict__ x_flat, const float* __restrict__ m_f,
          const float* __restrict__ m_r, const float* __restrict__ f_flat,
          const float* __restrict__ aw, float* __restrict__ xm)
{
    size_t idx = (size_t)blockIdx.x*256 + threadIdx.x;
    int d = (int)(idx % DIMD);
    size_t row = idx / DIMD;
    int b = (int)(row >> 13);
    float a0 = aw[(size_t)(b*3+0)*DIMD + d];
    float a1 = aw[(size_t)(b*3+1)*DIMD + d];
    float a2 = aw[(size_t)(b*3+2)*DIMD + d];
    xm[idx] = x_flat[idx] + a0*m_f[idx] + a1*m_r[idx] + a2*f_flat[idx];
}

// ============ depthwise 3x3x3 conv over (NF,H,W) + bias + exact GELU (bf16 out) ============
__global__ __launch_bounds__(256)
void k_dwconv(const float* __restrict__ h1, const float* __restrict__ dww,
              const float* __restrict__ dwb, unsigned short* __restrict__ h2)
{
    int c = blockIdx.x*256 + threadIdx.x;
    int h = blockIdx.y;
    int bnf = blockIdx.z; int b = bnf >> 3, nf = bnf & 7;
    float wt[27];
    #pragma unroll
    for (int i = 0; i < 27; ++i) wt[i] = dww[(size_t)c*27 + i];
    float bias = dwb[c];
    bool nfok[3], hok[3];
    #pragma unroll
    for (int dd = 0; dd < 3; ++dd){
        nfok[dd] = (nf+dd-1) >= 0 && (nf+dd-1) < NFR;
        hok[dd]  = (h+dd-1)  >= 0 && (h+dd-1)  < HH;
    }
    const float* base = h1 + (size_t)b*LSEQ*HID + c;
    float win[3][3][3];
    #pragma unroll
    for (int dn = 0; dn < 3; ++dn)
        #pragma unroll
        for (int dh = 0; dh < 3; ++dh){
            bool ok = nfok[dn] && hok[dh];
            size_t rb = ((size_t)(nf+dn-1)*1024 + (size_t)(h+dh-1)*32);
            win[dn][dh][0] = 0.f;
            win[dn][dh][1] = ok ? base[(rb + 0)*HID] : 0.f;
            win[dn][dh][2] = ok ? base[(rb + 1)*HID] : 0.f;
        }
    for (int xw = 0; xw < WW; ++xw){
        float acc = bias;
        #pragma unroll
        for (int dn = 0; dn < 3; ++dn)
            #pragma unroll
            for (int dh = 0; dh < 3; ++dh)
                #pragma unroll
                for (int dw = 0; dw < 3; ++dw)
                    acc += win[dn][dh][dw] * wt[dn*9 + dh*3 + dw];
        h2[((size_t)b*LSEQ + nf*1024 + h*32 + xw)*HID + c] = f2bf(geluf(acc));
        int wn = xw + 2;
        #pragma unroll
        for (int dn = 0; dn < 3; ++dn)
            #pragma unroll
            for (int dh = 0; dh < 3; ++dh){
                win[dn][dh][0] = win[dn][dh][1];
                win[dn][dh][1] = win[dn][dh][2];
                bool ok = (wn < WW) && nfok[dn] && hok[dh];
                size_t rb = ((size_t)(nf+dn-1)*1024 + (size_t)(h+dh-1)*32);
                win[dn][dh][2] = ok ? base[(rb + wn)*HID] : 0.f;
            }
    }
}

// ================================================================
extern "C" void kernel_launch(void* const* d_in, const int* in_sizes, int n_in,
                              void* d_out, int out_size, void* d_ws, size_t ws_size,
                              hipStream_t stream)
{
    const float* x     = (const float*)d_in[0];
    const float* fx    = (const float*)d_in[1];
    const int*   hc    = (const int*)  d_in[2];
    const float* ln1w  = (const float*)d_in[3];
    const float* ln1b  = (const float*)d_in[4];
    const float* inpw  = (const float*)d_in[5];
    const float* convw = (const float*)d_in[6];
    const float* convb = (const float*)d_in[7];
    const float* xpw   = (const float*)d_in[8];
    const float* dtw   = (const float*)d_in[9];
    const float* dtb   = (const float*)d_in[10];
    const float* alog  = (const float*)d_in[11];
    const float* dp    = (const float*)d_in[12];
    const float* outpw = (const float*)d_in[13];
    const float* ssaw  = (const float*)d_in[14];
    const float* ln2w  = (const float*)d_in[15];
    const float* ln2b  = (const float*)d_in[16];
    const float* fc1w  = (const float*)d_in[17];
    const float* fc1b  = (const float*)d_in[18];
    const float* dww   = (const float*)d_in[19];
    const float* dwb   = (const float*)d_in[20];
    const float* fc2w  = (const float*)d_in[21];
    const float* fc2b  = (const float*)d_in[22];

    float* ws = (float*)d_ws;
    float* x_flat = ws + OFF_XFLAT;
    float* f_flat = ws + OFF_FFLAT;
    float* xz     = ws + OFF_XZ;
    float* xc_f   = ws + OFF_XCF;
    float* xc_r   = ws + OFF_XCR;
    float* dbl_f  = ws + OFF_DBLF;
    float* dbl_r  = ws + OFF_DBLR;
    float* dt_f   = ws + OFF_DTF;
    float* dt_r   = ws + OFF_DTR;
    float* m_f    = ws + OFF_MF;
    float* m_r    = ws + OFF_MR_;
    float* h1     = ws + OFF_H1;
    float* xm     = ws + OFF_XM;
    float* part   = ws + OFF_PART;
    float* aw     = ws + OFF_AW;
    float* cA     = ws + OFF_CA;
    float* cB     = ws + OFF_CB;
    float* cH     = ws + OFF_CHS;
    unsigned short* nrm_bf = (unsigned short*)(ws + OFF_NORM);
    unsigned short* gf_bf  = (unsigned short*)(ws + OFF_GF);
    unsigned short* gr_bf  = (unsigned short*)(ws + OFF_GR);
    unsigned short* h2_bf  = (unsigned short*)(ws + OFF_H2);
    float* outp   = (float*)d_out;

    // 1. gather + LN1 (bf16 normed)
    k_gather_ln<<<MR, 128, 0, stream>>>(x, fx, hc, ln1w, ln1b, x_flat, f_flat, nrm_bf);
    // 2. in_proj (MFMA bf16, shared by fwd & rev)
    k_bgemm<0><<<dim3(128,3), 256, 0, stream>>>(nrm_bf, inpw, nullptr, nullptr, nullptr, xz, DIMD, DIMD);
    // 3. causal/anti-causal depthwise conv + silu
    k_conv<<<dim3(LSEQ/64, B_N), 256, 0, stream>>>(xz, convw, convb, xc_f, xc_r);
    // 4. x-proj (dbl = [dt_raw, B, C])
    k_dbl<<<MR/16, 256, 0, stream>>>(xc_f, xpw, dbl_f);
    k_dbl<<<MR/16, 256, 0, stream>>>(xc_r, xpw, dbl_r);
    // 5. dt projection + softplus
    k_dt<<<MR, 192, 0, stream>>>(dbl_f, dtw, dtb, dt_f);
    k_dt<<<MR, 192, 0, stream>>>(dbl_r, dtw, dtb, dt_r);
    // 6. chunked selective scans (both dirs; nrm_bf dead here)
    k_scan_p1<<<dim3(12*NCH, B_N, 2), 256, 0, stream>>>(dt_f, dt_r, dbl_f, dbl_r, xc_f, xc_r, alog, cA, cB);
    k_scan_p2<<<dim3(12, B_N, 2), 256, 0, stream>>>(cA, cB, cH);
    k_scan_p3<<<dim3(12*NCH, B_N, 2), 256, 0, stream>>>(dt_f, dt_r, dbl_f, dbl_r, xc_f, xc_r, xz, alog, dp, cH, gf_bf, gr_bf);
    // 7. out_proj (MFMA bf16)
    k_bgemm<0><<<dim3(128,3), 256, 0, stream>>>(gf_bf, outpw, nullptr, nullptr, nullptr, m_f, DIMD, DI);
    k_bgemm<0><<<dim3(128,3), 256, 0, stream>>>(gr_bf, outpw, nullptr, nullptr, nullptr, m_r, DIMD, DI);
    // 8. SSA
    k_pool<<<dim3(6,16), 256, 0, stream>>>(m_f, m_r, f_flat, part);
    k_ssa<<<B_N, 384, 0, stream>>>(part, ssaw, aw);
    k_xm<<<(unsigned)(SZ_BLD/256), 256, 0, stream>>>(x_flat, m_f, m_r, f_flat, aw, xm);
    // 9. MLP
    k_ln<<<MR, 128, 0, stream>>>(xm, ln2w, ln2b, nrm_bf);
    k_bgemm<1><<<dim3(128,12), 256, 0, stream>>>(nrm_bf, fc1w, fc1b, nullptr, nullptr, h1, HID, DIMD);
    k_dwconv<<<dim3(6,32,16), 256, 0, stream>>>(h1, dww, dwb, h2_bf);
    // 10. fc2 + residual + hilbert scatter to output (MFMA bf16)
    k_bgemm<2><<<dim3(128,3), 256, 0, stream>>>(h2_bf, fc2w, fc2b, xm, hc, outp, DIMD, HID);
}

// Round 4
// 900.907 us; speedup vs baseline: 8.5527x; 1.3184x over previous
//
#include <hip/hip_runtime.h>
#include <cmath>

#define B_N 2
#define NFR 8
#define HH 32
#define WW 32
#define LSEQ 8192
#define DIMD 384
#define DI 192
#define DST 16
#define DRK 24
#define HID 1536
#define MR (B_N*LSEQ)   // 16384 rows

#define NCH 64          // scan chunks
#define CL  (LSEQ/NCH)  // 128 steps per chunk
#define PSL 128         // pool slices

typedef __attribute__((ext_vector_type(8))) short  bf16x8;
typedef __attribute__((ext_vector_type(4))) float  f32x4;
typedef __attribute__((ext_vector_type(8))) unsigned short u16x8;

// ---------------- workspace layout (floats) ----------------
constexpr size_t SZ_BLD = (size_t)MR * DIMD;   // 6291456
constexpr size_t SZ_BLI = (size_t)MR * DI;     // 3145728
constexpr size_t SZ_DBL = (size_t)MR * 56;     // 917504

constexpr size_t OFF_XFLAT = 0;
constexpr size_t OFF_FFLAT = OFF_XFLAT + SZ_BLD;
constexpr size_t OFF_XZ    = OFF_FFLAT + SZ_BLD;
constexpr size_t OFF_XCF   = OFF_XZ + SZ_BLD;
constexpr size_t OFF_XCR   = OFF_XCF + SZ_BLI;
// region1 = [0, 25165824) ; h1 aliases it exactly (dead by fc1 time)
constexpr size_t OFF_H1    = 0;
constexpr size_t OFF_R2    = OFF_XCR + SZ_BLI;      // 25165824
constexpr size_t OFF_DBLF  = OFF_R2;
constexpr size_t OFF_DBLR  = OFF_DBLF + SZ_DBL;
constexpr size_t OFF_DTF   = OFF_DBLR + SZ_DBL;
constexpr size_t OFF_DTR   = OFF_DTF + SZ_BLI;
constexpr size_t OFF_GF    = OFF_DTR + SZ_BLI;      // bf16 g_f (as shorts)
constexpr size_t OFF_GR    = OFF_GF + SZ_BLI;       // bf16 g_r
constexpr size_t OFF_MF    = OFF_GR + SZ_BLI;
constexpr size_t OFF_MR_   = OFF_MF + SZ_BLD;
constexpr size_t OFF_H2    = OFF_R2;                // bf16 h2 (as shorts; dbl..m dead by dwconv)
constexpr size_t OFF_NORM  = OFF_MR_ + SZ_BLD;      // bf16 normed1 / normed2 (as shorts)
constexpr size_t OFF_XM    = OFF_NORM + SZ_BLD;
constexpr size_t OFF_PART  = OFF_XM + SZ_BLD;
constexpr size_t OFF_AW    = OFF_PART + (size_t)6*PSL*384;
// scan chunk summaries alias the (dead-at-scan-time) normed region:
constexpr size_t SZ_CH   = (size_t)2*B_N*12*NCH*256;      // 786432
constexpr size_t OFF_CA  = OFF_NORM;
constexpr size_t OFF_CB  = OFF_CA + SZ_CH;
constexpr size_t OFF_CHS = OFF_CB + SZ_CH;                // < OFF_NORM + SZ_BLD

__device__ __forceinline__ float siluf(float x){ return x / (1.f + expf(-x)); }
__device__ __forceinline__ float softplusf(float x){ return x > 20.f ? x : log1pf(expf(x)); }
__device__ __forceinline__ float geluf(float x){ return 0.5f * x * (1.f + erff(x * 0.70710678118f)); }
__device__ __forceinline__ unsigned short f2bf(float f){
    union { float f; unsigned int u; } v; v.f = f;
    unsigned int u = v.u + 0x7fffu + ((v.u >> 16) & 1u);
    return (unsigned short)(u >> 16);
}

#if __has_builtin(__builtin_amdgcn_global_load_lds)
#define HAVE_GLL 1
__device__ __forceinline__ void gload16(const void* g, void* l){
    __builtin_amdgcn_global_load_lds((const __attribute__((address_space(1))) void*)g,
                                     (__attribute__((address_space(3))) void*)l, 16, 0, 0);
}
#else
#define HAVE_GLL 0
#endif

// ============ K1: hilbert gather (x, freq_x) + LayerNorm1 (bf16 out) ============
__global__ __launch_bounds__(128)
void k_gather_ln(const float* __restrict__ x, const float* __restrict__ fx,
                 const int* __restrict__ hc, const float* __restrict__ lw,
                 const float* __restrict__ lb, float* __restrict__ x_flat,
                 float* __restrict__ f_flat, unsigned short* __restrict__ normed)
{
    int blk = blockIdx.x;            // b*L + l
    int b = blk >> 13, l = blk & (LSEQ-1);
    int p = hc[l];
    int nf = p >> 10, hw = p & 1023;
    const float* xb = x  + ((size_t)(b*NFR+nf)*DIMD)*1024 + hw;
    const float* fb = fx + ((size_t)(b*NFR+nf)*DIMD)*1024 + hw;
    int t = threadIdx.x;
    float v[3]; float s = 0.f, s2 = 0.f;
    #pragma unroll
    for (int i = 0; i < 3; ++i){
        int d = t + i*128;
        float a = xb[(size_t)d*1024];
        v[i] = a; s += a; s2 += a*a;
        x_flat[(size_t)blk*DIMD + d] = a;
        f_flat[(size_t)blk*DIMD + d] = fb[(size_t)d*1024];
    }
    #pragma unroll
    for (int o = 32; o > 0; o >>= 1){ s += __shfl_down(s, o); s2 += __shfl_down(s2, o); }
    __shared__ float sh[4];
    if ((t & 63) == 0){ sh[(t>>6)*2] = s; sh[(t>>6)*2+1] = s2; }
    __syncthreads();
    float S = sh[0] + sh[2], S2 = sh[1] + sh[3];
    float mean = S * (1.f/DIMD);
    float var  = S2 * (1.f/DIMD) - mean*mean;
    float r = rsqrtf(var + 1e-5f);
    #pragma unroll
    for (int i = 0; i < 3; ++i){
        int d = t + i*128;
        normed[(size_t)blk*DIMD + d] = f2bf((v[i]-mean)*r*lw[d] + lb[d]);
    }
}

// ============ plain row LayerNorm (LN2), bf16 out ============
__global__ __launch_bounds__(128)
void k_ln(const float* __restrict__ in, const float* __restrict__ lw,
          const float* __restrict__ lb, unsigned short* __restrict__ out)
{
    size_t row = blockIdx.x;
    int t = threadIdx.x;
    float v[3]; float s = 0.f, s2 = 0.f;
    #pragma unroll
    for (int i = 0; i < 3; ++i){
        int d = t + i*128;
        float a = in[row*DIMD + d];
        v[i] = a; s += a; s2 += a*a;
    }
    #pragma unroll
    for (int o = 32; o > 0; o >>= 1){ s += __shfl_down(s, o); s2 += __shfl_down(s2, o); }
    __shared__ float sh[4];
    if ((t & 63) == 0){ sh[(t>>6)*2] = s; sh[(t>>6)*2+1] = s2; }
    __syncthreads();
    float S = sh[0] + sh[2], S2 = sh[1] + sh[3];
    float mean = S * (1.f/DIMD);
    float var  = S2 * (1.f/DIMD) - mean*mean;
    float r = rsqrtf(var + 1e-5f);
    #pragma unroll
    for (int i = 0; i < 3; ++i){
        int d = t + i*128;
        out[row*DIMD + d] = f2bf((v[i]-mean)*r*lw[d] + lb[d]);
    }
}

// ============ bf16 MFMA GEMM: C[M,N] = A[M,K](bf16) @ W[N,K](f32->bf16)^T ============
// EPI 0: plain f32 store.  EPI 1: +bias.  EPI 2: +bias +add(xm), scatter via hilbert.
template<int EPI>
__global__ __launch_bounds__(256, 2)
void k_bgemm(const unsigned short* __restrict__ A, const float* __restrict__ Wf,
             const float* __restrict__ bias, const float* __restrict__ add,
             const int* __restrict__ hc, float* __restrict__ C, int N, int K)
{
    __shared__ unsigned short As[128*32];   // linear [128 rows][32 k]
    __shared__ unsigned short Bs[128*48];   // padded [128 rows][48] (32 used)
    int tid  = threadIdx.x;
    int wid  = tid >> 6, lane = tid & 63;
    int row0 = blockIdx.x * 128, col0 = blockIdx.y * 128;
    int wr = wid >> 1, wc = wid & 1;        // wave tile: 64x64
    int lr = lane & 15, lg = lane >> 4;

    f32x4 acc[4][4];
    #pragma unroll
    for (int m = 0; m < 4; ++m)
        #pragma unroll
        for (int n = 0; n < 4; ++n) acc[m][n] = (f32x4){0.f,0.f,0.f,0.f};

    // A staging geometry: slot byte s = wid*2048 + i*1024 + lane*16
    int sA0 = wid*2048 + lane*16;
    int rA0 = sA0 >> 6, kA0 = (sA0 & 63) >> 1;
    int sA1 = sA0 + 1024;
    int rA1 = sA1 >> 6, kA1 = (sA1 & 63) >> 1;
    const unsigned short* Ag0 = A + (size_t)(row0 + rA0)*K + kA0;
    const unsigned short* Ag1 = A + (size_t)(row0 + rA1)*K + kA1;
    // B staging: thread -> (n = tid>>1, kpart = (tid&1)*16)
    int bn = tid >> 1, bkp = (tid & 1) * 16;
    const float* Wg = Wf + (size_t)(col0 + bn)*K + bkp;

    const unsigned short* Ab = &As[(wr*64 + lr)*32 + lg*8];
    const unsigned short* Bb = &Bs[(wc*64 + lr)*48 + lg*8];
    unsigned short* Bw = &Bs[bn*48 + bkp];

    for (int k0 = 0; k0 < K; k0 += 32){
        if (k0) __syncthreads();
#if HAVE_GLL
        gload16(Ag0, (char*)As + wid*2048);
        gload16(Ag1, (char*)As + wid*2048 + 1024);
#else
        *(u16x8*)((char*)As + sA0) = *(const u16x8*)Ag0;
        *(u16x8*)((char*)As + sA1) = *(const u16x8*)Ag1;
#endif
        Ag0 += 32; Ag1 += 32;
        {
            float4 f0 = *(const float4*)(Wg+0);
            float4 f1 = *(const float4*)(Wg+4);
            float4 f2 = *(const float4*)(Wg+8);
            float4 f3 = *(const float4*)(Wg+12);
            Wg += 32;
            u16x8 p0, p1;
            p0[0]=f2bf(f0.x); p0[1]=f2bf(f0.y); p0[2]=f2bf(f0.z); p0[3]=f2bf(f0.w);
            p0[4]=f2bf(f1.x); p0[5]=f2bf(f1.y); p0[6]=f2bf(f1.z); p0[7]=f2bf(f1.w);
            p1[0]=f2bf(f2.x); p1[1]=f2bf(f2.y); p1[2]=f2bf(f2.z); p1[3]=f2bf(f2.w);
            p1[4]=f2bf(f3.x); p1[5]=f2bf(f3.y); p1[6]=f2bf(f3.z); p1[7]=f2bf(f3.w);
            *(u16x8*)(Bw)     = p0;
            *(u16x8*)(Bw + 8) = p1;
        }
        __syncthreads();
        bf16x8 af[4], bfr[4];
        #pragma unroll
        for (int m = 0; m < 4; ++m) af[m]  = *(const bf16x8*)(Ab + m*512);   // m*16*32
        #pragma unroll
        for (int n = 0; n < 4; ++n) bfr[n] = *(const bf16x8*)(Bb + n*768);   // n*16*48
        #pragma unroll
        for (int m = 0; m < 4; ++m)
            #pragma unroll
            for (int n = 0; n < 4; ++n)
                acc[m][n] = __builtin_amdgcn_mfma_f32_16x16x32_bf16(af[m], bfr[n], acc[m][n], 0, 0, 0);
    }

    // epilogue: D row = (lane>>4)*4 + r, col = lane&15 within each 16x16 frag
    #pragma unroll
    for (int m = 0; m < 4; ++m){
        #pragma unroll
        for (int r = 0; r < 4; ++r){
            int row = row0 + wr*64 + m*16 + lg*4 + r;
            if (EPI == 2){
                int bb = row >> 13, l = row & (LSEQ-1);
                int p = hc[l];
                size_t obase = ((size_t)(bb*NFR + (p>>10))*DIMD)*1024 + (p & 1023);
                #pragma unroll
                for (int n = 0; n < 4; ++n){
                    int col = col0 + wc*64 + n*16 + lr;
                    float v = acc[m][n][r] + bias[col] + add[(size_t)row*N + col];
                    C[obase + (size_t)col*1024] = v;
                }
            } else {
                #pragma unroll
                for (int n = 0; n < 4; ++n){
                    int col = col0 + wc*64 + n*16 + lr;
                    float v = acc[m][n][r];
                    if (EPI == 1) v += bias[col];
                    C[(size_t)row*N + col] = v;
                }
            }
        }
    }
}

// ============ causal + anti-causal depthwise conv over L, + silu ============
__global__ __launch_bounds__(256)
void k_conv(const float* __restrict__ xz, const float* __restrict__ cw,
            const float* __restrict__ cb, float* __restrict__ xcf, float* __restrict__ xcr)
{
    const int TL = 64;
    int b = blockIdx.y;
    int l0 = blockIdx.x * TL;
    __shared__ float sx[TL+6][DI];   // rows hold l0-3 .. l0+TL+2
    for (int idx = threadIdx.x; idx < (TL+6)*DI; idx += 256){
        int r = idx / DI, c = idx % DI;
        int l = l0 + r - 3;
        float v = 0.f;
        if (l >= 0 && l < LSEQ) v = xz[((size_t)b*LSEQ + l)*DIMD + c];
        sx[r][c] = v;
    }
    __syncthreads();
    for (int idx = threadIdx.x; idx < TL*DI; idx += 256){
        int r = idx / DI, c = idx % DI;
        float w0 = cw[c*4+0], w1 = cw[c*4+1], w2 = cw[c*4+2], w3 = cw[c*4+3];
        float bi = cb[c];
        size_t orow = ((size_t)b*LSEQ + l0 + r)*DI + c;
        float af = bi + sx[r][c]*w0 + sx[r+1][c]*w1 + sx[r+2][c]*w2 + sx[r+3][c]*w3;
        xcf[orow] = siluf(af);
        float ar = bi + sx[r+3][c]*w3 + sx[r+4][c]*w2 + sx[r+5][c]*w1 + sx[r+6][c]*w0;
        xcr[orow] = siluf(ar);
    }
}

// ============ dbl = xc @ xproj_w^T  (N=56, K=192) ============
__global__ __launch_bounds__(256)
void k_dbl(const float* __restrict__ xc, const float* __restrict__ xpw, float* __restrict__ dbl)
{
    __shared__ float sw[56*193];
    for (int i = threadIdx.x; i < 56*DI; i += 256){
        int n = i / DI, k = i % DI;
        sw[n*193 + k] = xpw[i];
    }
    __syncthreads();
    int n = threadIdx.x & 63;
    int ri = threadIdx.x >> 6;
    int row0 = blockIdx.x * 16;
    if (n < 56){
        for (int rp = 0; rp < 4; ++rp){
            int row = row0 + rp*4 + ri;
            const float* xr = xc + (size_t)row*DI;
            float acc = 0.f;
            #pragma unroll 8
            for (int k = 0; k < DI; ++k) acc += xr[k] * sw[n*193 + k];
            dbl[(size_t)row*56 + n] = acc;
        }
    }
}

// ============ dt = softplus(dbl[:, :24] @ dt_w^T + dt_b)  (N=192, K=24) ============
__global__ __launch_bounds__(192)
void k_dt(const float* __restrict__ dbl, const float* __restrict__ dtw,
          const float* __restrict__ dtb, float* __restrict__ dt)
{
    int row = blockIdx.x;
    int d = threadIdx.x;
    __shared__ float sd[24];
    if (d < 24) sd[d] = dbl[(size_t)row*56 + d];
    __syncthreads();
    float acc = dtb[d];
    #pragma unroll
    for (int r = 0; r < DRK; ++r) acc += sd[r] * dtw[d*DRK + r];
    dt[(size_t)row*DI + d] = softplusf(acc);
}

// ============ chunked selective scan ============
// p1: per-chunk composed (A = prod da, B = local scan from h=0)
__global__ __launch_bounds__(256)
void k_scan_p1(const float* __restrict__ dt_f, const float* __restrict__ dt_r,
               const float* __restrict__ dbl_f, const float* __restrict__ dbl_r,
               const float* __restrict__ xc_f, const float* __restrict__ xc_r,
               const float* __restrict__ A_log,
               float* __restrict__ CA, float* __restrict__ CB)
{
    int dir = blockIdx.z;
    int b   = blockIdx.y;
    int dg  = blockIdx.x >> 6;       // 0..11
    int ch  = blockIdx.x & (NCH-1);  // 0..63
    const float* dt  = dir ? dt_r  : dt_f;
    const float* dbl = dir ? dbl_r : dbl_f;
    const float* xc  = dir ? xc_r  : xc_f;
    int d0 = dg*16;
    int tid = threadIdx.x;
    int s = tid & 15, di = tid >> 4;
    int d = d0 + di;
    float A2 = -expf(A_log[d*DST + s]) * 1.44269504f;
    float hA = 1.f, hB = 0.f;
    __shared__ float sdt[16][16], sxv[16][16], sB[16][16];
    int r = tid >> 4, cix = tid & 15;
    for (int sub = 0; sub < CL/16; ++sub){
        __syncthreads();
        int lidx = ch*CL + sub*16 + r;
        int lld = dir ? (LSEQ-1-lidx) : lidx;
        size_t rowbl = (size_t)b*LSEQ + lld;
        sdt[r][cix] = dt[rowbl*DI + d0 + cix];
        sxv[r][cix] = xc[rowbl*DI + d0 + cix];
        sB[r][cix]  = dbl[rowbl*56 + 24 + cix];
        __syncthreads();
        #pragma unroll
        for (int j = 0; j < 16; ++j){
            float dtv = sdt[j][di];
            float da  = exp2f(dtv * A2);
            float db  = dtv * sB[j][s] * sxv[j][di];
            hA *= da;
            hB = da*hB + db;
        }
    }
    size_t o = ((((size_t)dir*B_N + b)*12 + dg)*NCH + ch)*256 + tid;
    CA[o] = hA; CB[o] = hB;
}

// p2: sequential combine over chunk summaries -> incoming state per chunk
__global__ __launch_bounds__(256)
void k_scan_p2(const float* __restrict__ CA, const float* __restrict__ CB,
               float* __restrict__ CH)
{
    int dir = blockIdx.z, b = blockIdx.y, dg = blockIdx.x;
    int tid = threadIdx.x;
    size_t base = ((((size_t)dir*B_N + b)*12 + dg)*NCH)*256 + tid;
    float h = 0.f;
    for (int c = 0; c < NCH; ++c){
        size_t o = base + (size_t)c*256;
        CH[o] = h;
        h = CA[o]*h + CB[o];
    }
}

// p3: rescan from h_in, compute y, gate, write g (bf16)
__global__ __launch_bounds__(256)
void k_scan_p3(const float* __restrict__ dt_f, const float* __restrict__ dt_r,
               const float* __restrict__ dbl_f, const float* __restrict__ dbl_r,
               const float* __restrict__ xc_f, const float* __restrict__ xc_r,
               const float* __restrict__ xz, const float* __restrict__ A_log,
               const float* __restrict__ Dp, const float* __restrict__ CH,
               unsigned short* __restrict__ g_f, unsigned short* __restrict__ g_r)
{
    int dir = blockIdx.z;
    int b   = blockIdx.y;
    int dg  = blockIdx.x >> 6;
    int ch  = blockIdx.x & (NCH-1);
    const float* dt  = dir ? dt_r  : dt_f;
    const float* dbl = dir ? dbl_r : dbl_f;
    const float* xc  = dir ? xc_r  : xc_f;
    unsigned short* g = dir ? g_r : g_f;
    int d0 = dg*16;
    int tid = threadIdx.x;
    int s = tid & 15, di = tid >> 4;
    int d = d0 + di;
    float A2  = -expf(A_log[d*DST + s]) * 1.44269504f;
    float Dpd = Dp[d];
    float h = CH[((((size_t)dir*B_N + b)*12 + dg)*NCH + ch)*256 + tid];
    __shared__ float sdt[16][16], sxv[16][16], szv[16][16], sB[16][16], sC[16][16];
    int r = tid >> 4, cix = tid & 15;
    for (int sub = 0; sub < CL/16; ++sub){
        __syncthreads();
        int lidx = ch*CL + sub*16 + r;
        int lld = dir ? (LSEQ-1-lidx) : lidx;
        size_t rowbl = (size_t)b*LSEQ + lld;
        sdt[r][cix] = dt[rowbl*DI + d0 + cix];
        sxv[r][cix] = xc[rowbl*DI + d0 + cix];
        szv[r][cix] = xz[rowbl*DIMD + DI + d0 + cix];
        sB[r][cix]  = dbl[rowbl*56 + 24 + cix];
        sC[r][cix]  = dbl[rowbl*56 + 40 + cix];
        __syncthreads();
        #pragma unroll 4
        for (int j = 0; j < 16; ++j){
            float dtv = sdt[j][di];
            float xv  = sxv[j][di];
            float da  = exp2f(dtv * A2);
            float db  = dtv * sB[j][s] * xv;
            h = da*h + db;
            float yc = h * sC[j][s];
            yc += __shfl_xor(yc, 8);
            yc += __shfl_xor(yc, 4);
            yc += __shfl_xor(yc, 2);
            yc += __shfl_xor(yc, 1);
            if (s == 0){
                float zv = szv[j][di];
                int lidxj = ch*CL + sub*16 + j;
                int lw = dir ? (LSEQ-1-lidxj) : lidxj;
                g[((size_t)b*LSEQ + lw)*DI + d] = f2bf((yc + Dpd*xv) * siluf(zv));
            }
        }
    }
}

// ============ pooled partial sums over L (for SSA) — high-parallelism ============
__global__ __launch_bounds__(384)
void k_pool(const float* __restrict__ m_f, const float* __restrict__ m_r,
            const float* __restrict__ f_flat, float* __restrict__ partial)
{
    int bt = blockIdx.x;      // b*3 + t
    int sl = blockIdx.y;      // PSL slices of LSEQ/PSL rows
    int b = bt / 3, t = bt % 3;
    const float* src = (t == 0) ? m_f : (t == 1) ? m_r : f_flat;
    src += (size_t)b*LSEQ*DIMD + (size_t)sl*(LSEQ/PSL)*DIMD;
    int d = threadIdx.x;
    float sum = 0.f;
    #pragma unroll 8
    for (int l = 0; l < LSEQ/PSL; ++l) sum += src[(size_t)l*DIMD + d];
    partial[((size_t)bt*PSL + sl)*DIMD + d] = sum;
}

// ============ SSA attention weights: softmax over t ============
__global__ __launch_bounds__(384)
void k_ssa(const float* __restrict__ partial, const float* __restrict__ ssaw,
           float* __restrict__ aw)
{
    int b = blockIdx.x;
    int d = threadIdx.x;
    float pooled[3];
    #pragma unroll
    for (int t = 0; t < 3; ++t){
        float sum = 0.f;
        for (int sl = 0; sl < PSL; ++sl) sum += partial[((size_t)(b*3+t)*PSL + sl)*DIMD + d];
        pooled[t] = sum * (1.f/LSEQ);
    }
    float wv[3];
    #pragma unroll
    for (int t = 0; t < 3; ++t)
        wv[t] = pooled[0]*ssaw[d*9 + t*3 + 0] + pooled[1]*ssaw[d*9 + t*3 + 1] + pooled[2]*ssaw[d*9 + t*3 + 2];
    float mx = fmaxf(wv[0], fmaxf(wv[1], wv[2]));
    float e0 = expf(wv[0]-mx), e1 = expf(wv[1]-mx), e2 = expf(wv[2]-mx);
    float inv = 1.f / (e0+e1+e2);
    aw[(size_t)(b*3+0)*DIMD + d] = e0*inv;
    aw[(size_t)(b*3+1)*DIMD + d] = e1*inv;
    aw[(size_t)(b*3+2)*DIMD + d] = e2*inv;
}

// ============ xm = x_flat + sum_t aw[t]*seq_t ============
__global__ __launch_bounds__(256)
void k_xm(const float* __restrict__ x_flat, const float* __restrict__ m_f,
          const float* __restrict__ m_r, const float* __restrict__ f_flat,
          const float* __restrict__ aw, float* __restrict__ xm)
{
    size_t idx = (size_t)blockIdx.x*256 + threadIdx.x;
    int d = (int)(idx % DIMD);
    size_t row = idx / DIMD;
    int b = (int)(row >> 13);
    float a0 = aw[(size_t)(b*3+0)*DIMD + d];
    float a1 = aw[(size_t)(b*3+1)*DIMD + d];
    float a2 = aw[(size_t)(b*3+2)*DIMD + d];
    xm[idx] = x_flat[idx] + a0*m_f[idx] + a1*m_r[idx] + a2*f_flat[idx];
}

// ============ depthwise 3x3x3 conv over (NF,H,W) + bias + exact GELU (bf16 out) ============
__global__ __launch_bounds__(256)
void k_dwconv(const float* __restrict__ h1, const float* __restrict__ dww,
              const float* __restrict__ dwb, unsigned short* __restrict__ h2)
{
    int c = blockIdx.x*256 + threadIdx.x;
    int h = blockIdx.y;
    int bnf = blockIdx.z; int b = bnf >> 3, nf = bnf & 7;
    float wt[27];
    #pragma unroll
    for (int i = 0; i < 27; ++i) wt[i] = dww[(size_t)c*27 + i];
    float bias = dwb[c];
    bool nfok[3], hok[3];
    #pragma unroll
    for (int dd = 0; dd < 3; ++dd){
        nfok[dd] = (nf+dd-1) >= 0 && (nf+dd-1) < NFR;
        hok[dd]  = (h+dd-1)  >= 0 && (h+dd-1)  < HH;
    }
    const float* base = h1 + (size_t)b*LSEQ*HID + c;
    float win[3][3][3];
    #pragma unroll
    for (int dn = 0; dn < 3; ++dn)
        #pragma unroll
        for (int dh = 0; dh < 3; ++dh){
            bool ok = nfok[dn] && hok[dh];
            size_t rb = ((size_t)(nf+dn-1)*1024 + (size_t)(h+dh-1)*32);
            win[dn][dh][0] = 0.f;
            win[dn][dh][1] = ok ? base[(rb + 0)*HID] : 0.f;
            win[dn][dh][2] = ok ? base[(rb + 1)*HID] : 0.f;
        }
    for (int xw = 0; xw < WW; ++xw){
        float acc = bias;
        #pragma unroll
        for (int dn = 0; dn < 3; ++dn)
            #pragma unroll
            for (int dh = 0; dh < 3; ++dh)
                #pragma unroll
                for (int dw = 0; dw < 3; ++dw)
                    acc += win[dn][dh][dw] * wt[dn*9 + dh*3 + dw];
        h2[((size_t)b*LSEQ + nf*1024 + h*32 + xw)*HID + c] = f2bf(geluf(acc));
        int wn = xw + 2;
        #pragma unroll
        for (int dn = 0; dn < 3; ++dn)
            #pragma unroll
            for (int dh = 0; dh < 3; ++dh){
                win[dn][dh][0] = win[dn][dh][1];
                win[dn][dh][1] = win[dn][dh][2];
                bool ok = (wn < WW) && nfok[dn] && hok[dh];
                size_t rb = ((size_t)(nf+dn-1)*1024 + (size_t)(h+dh-1)*32);
                win[dn][dh][2] = ok ? base[(rb + wn)*HID] : 0.f;
            }
    }
}

// ================================================================
extern "C" void kernel_launch(void* const* d_in, const int* in_sizes, int n_in,
                              void* d_out, int out_size, void* d_ws, size_t ws_size,
                              hipStream_t stream)
{
    const float* x     = (const float*)d_in[0];
    const float* fx    = (const float*)d_in[1];
    const int*   hc    = (const int*)  d_in[2];
    const float* ln1w  = (const float*)d_in[3];
    const float* ln1b  = (const float*)d_in[4];
    const float* inpw  = (const float*)d_in[5];
    const float* convw = (const float*)d_in[6];
    const float* convb = (const float*)d_in[7];
    const float* xpw   = (const float*)d_in[8];
    const float* dtw   = (const float*)d_in[9];
    const float* dtb   = (const float*)d_in[10];
    const float* alog  = (const float*)d_in[11];
    const float* dp    = (const float*)d_in[12];
    const float* outpw = (const float*)d_in[13];
    const float* ssaw  = (const float*)d_in[14];
    const float* ln2w  = (const float*)d_in[15];
    const float* ln2b  = (const float*)d_in[16];
    const float* fc1w  = (const float*)d_in[17];
    const float* fc1b  = (const float*)d_in[18];
    const float* dww   = (const float*)d_in[19];
    const float* dwb   = (const float*)d_in[20];
    const float* fc2w  = (const float*)d_in[21];
    const float* fc2b  = (const float*)d_in[22];

    float* ws = (float*)d_ws;
    float* x_flat = ws + OFF_XFLAT;
    float* f_flat = ws + OFF_FFLAT;
    float* xz     = ws + OFF_XZ;
    float* xc_f   = ws + OFF_XCF;
    float* xc_r   = ws + OFF_XCR;
    float* dbl_f  = ws + OFF_DBLF;
    float* dbl_r  = ws + OFF_DBLR;
    float* dt_f   = ws + OFF_DTF;
    float* dt_r   = ws + OFF_DTR;
    float* m_f    = ws + OFF_MF;
    float* m_r    = ws + OFF_MR_;
    float* h1     = ws + OFF_H1;
    float* xm     = ws + OFF_XM;
    float* part   = ws + OFF_PART;
    float* aw     = ws + OFF_AW;
    float* cA     = ws + OFF_CA;
    float* cB     = ws + OFF_CB;
    float* cH     = ws + OFF_CHS;
    unsigned short* nrm_bf = (unsigned short*)(ws + OFF_NORM);
    unsigned short* gf_bf  = (unsigned short*)(ws + OFF_GF);
    unsigned short* gr_bf  = (unsigned short*)(ws + OFF_GR);
    unsigned short* h2_bf  = (unsigned short*)(ws + OFF_H2);
    float* outp   = (float*)d_out;

    // 1. gather + LN1 (bf16 normed)
    k_gather_ln<<<MR, 128, 0, stream>>>(x, fx, hc, ln1w, ln1b, x_flat, f_flat, nrm_bf);
    // 2. in_proj (MFMA bf16, shared by fwd & rev)
    k_bgemm<0><<<dim3(128,3), 256, 0, stream>>>(nrm_bf, inpw, nullptr, nullptr, nullptr, xz, DIMD, DIMD);
    // 3. causal/anti-causal depthwise conv + silu
    k_conv<<<dim3(LSEQ/64, B_N), 256, 0, stream>>>(xz, convw, convb, xc_f, xc_r);
    // 4. x-proj (dbl = [dt_raw, B, C])
    k_dbl<<<MR/16, 256, 0, stream>>>(xc_f, xpw, dbl_f);
    k_dbl<<<MR/16, 256, 0, stream>>>(xc_r, xpw, dbl_r);
    // 5. dt projection + softplus
    k_dt<<<MR, 192, 0, stream>>>(dbl_f, dtw, dtb, dt_f);
    k_dt<<<MR, 192, 0, stream>>>(dbl_r, dtw, dtb, dt_r);
    // 6. chunked selective scans (both dirs; nrm_bf dead here)
    k_scan_p1<<<dim3(12*NCH, B_N, 2), 256, 0, stream>>>(dt_f, dt_r, dbl_f, dbl_r, xc_f, xc_r, alog, cA, cB);
    k_scan_p2<<<dim3(12, B_N, 2), 256, 0, stream>>>(cA, cB, cH);
    k_scan_p3<<<dim3(12*NCH, B_N, 2), 256, 0, stream>>>(dt_f, dt_r, dbl_f, dbl_r, xc_f, xc_r, xz, alog, dp, cH, gf_bf, gr_bf);
    // 7. out_proj (MFMA bf16)
    k_bgemm<0><<<dim3(128,3), 256, 0, stream>>>(gf_bf, outpw, nullptr, nullptr, nullptr, m_f, DIMD, DI);
    k_bgemm<0><<<dim3(128,3), 256, 0, stream>>>(gr_bf, outpw, nullptr, nullptr, nullptr, m_r, DIMD, DI);
    // 8. SSA
    k_pool<<<dim3(6,PSL), 384, 0, stream>>>(m_f, m_r, f_flat, part);
    k_ssa<<<B_N, 384, 0, stream>>>(part, ssaw, aw);
    k_xm<<<(unsigned)(SZ_BLD/256), 256, 0, stream>>>(x_flat, m_f, m_r, f_flat, aw, xm);
    // 9. MLP
    k_ln<<<MR, 128, 0, stream>>>(xm, ln2w, ln2b, nrm_bf);
    k_bgemm<1><<<dim3(128,12), 256, 0, stream>>>(nrm_bf, fc1w, fc1b, nullptr, nullptr, h1, HID, DIMD);
    k_dwconv<<<dim3(6,32,16), 256, 0, stream>>>(h1, dww, dwb, h2_bf);
    // 10. fc2 + residual + hilbert scatter to output (MFMA bf16)
    k_bgemm<2><<<dim3(128,3), 256, 0, stream>>>(h2_bf, fc2w, fc2b, xm, hc, outp, DIMD, HID);
}

// Round 5
// 698.314 us; speedup vs baseline: 11.0340x; 1.2901x over previous
//
#include <hip/hip_runtime.h>
#include <cmath>

#define B_N 2
#define NFR 8
#define HH 32
#define WW 32
#define LSEQ 8192
#define DIMD 384
#define DI 192
#define DST 16
#define DRK 24
#define HID 1536
#define MR (B_N*LSEQ)   // 16384 rows

#define NCH 64          // scan chunks
#define CL  (LSEQ/NCH)  // 128 steps per chunk
#define PSL 128         // pool slices

typedef __attribute__((ext_vector_type(8))) short  bf16x8;
typedef __attribute__((ext_vector_type(4))) float  f32x4;
typedef __attribute__((ext_vector_type(8))) unsigned short u16x8;

// ---------------- workspace layout (floats) ----------------
constexpr size_t SZ_BLD = (size_t)MR * DIMD;   // 6291456
constexpr size_t SZ_BLI = (size_t)MR * DI;     // 3145728
constexpr size_t SZ_DBL = (size_t)MR * 56;     // 917504

constexpr size_t OFF_XFLAT = 0;
constexpr size_t OFF_FFLAT = OFF_XFLAT + SZ_BLD;
constexpr size_t OFF_XZ    = OFF_FFLAT + SZ_BLD;
constexpr size_t OFF_XCF   = OFF_XZ + SZ_BLD;
constexpr size_t OFF_XCR   = OFF_XCF + SZ_BLI;
// region1 = [0, 25165824) ; h1 aliases it exactly (dead by fc1 time)
constexpr size_t OFF_H1    = 0;
constexpr size_t OFF_R2    = OFF_XCR + SZ_BLI;      // 25165824
constexpr size_t OFF_DBLF  = OFF_R2;
constexpr size_t OFF_DBLR  = OFF_DBLF + SZ_DBL;
constexpr size_t OFF_DTF   = OFF_DBLR + SZ_DBL;
constexpr size_t OFF_DTR   = OFF_DTF + SZ_BLI;
constexpr size_t OFF_GF    = OFF_DTR + SZ_BLI;      // bf16 g_f (as shorts)
constexpr size_t OFF_GR    = OFF_GF + SZ_BLI;       // bf16 g_r
constexpr size_t OFF_MF    = OFF_GR + SZ_BLI;
constexpr size_t OFF_MR_   = OFF_MF + SZ_BLD;
constexpr size_t OFF_H2    = OFF_R2;                // bf16 h2 (as shorts; dbl..m dead by dwconv)
constexpr size_t OFF_NORM  = OFF_MR_ + SZ_BLD;      // bf16 normed1/2; later f32 outm
constexpr size_t OFF_XM    = OFF_NORM + SZ_BLD;
constexpr size_t OFF_PART  = OFF_XM + SZ_BLD;
constexpr size_t OFF_AW    = OFF_PART + (size_t)6*PSL*384;
constexpr size_t OFF_INV   = OFF_AW + 2*3*384;      // 8192 ints
// scan chunk summaries alias the (dead-at-scan-time) normed region:
constexpr size_t SZ_CH   = (size_t)2*B_N*12*NCH*256;      // 786432
constexpr size_t OFF_CA  = OFF_NORM;
constexpr size_t OFF_CB  = OFF_CA + SZ_CH;
constexpr size_t OFF_CHS = OFF_CB + SZ_CH;                // < OFF_NORM + SZ_BLD

__device__ __forceinline__ float siluf(float x){ return x / (1.f + expf(-x)); }
__device__ __forceinline__ float softplusf(float x){ return x > 20.f ? x : log1pf(expf(x)); }
__device__ __forceinline__ float geluf(float x){ return 0.5f * x * (1.f + erff(x * 0.70710678118f)); }
__device__ __forceinline__ unsigned short f2bf(float f){
    union { float f; unsigned int u; } v; v.f = f;
    unsigned int u = v.u + 0x7fffu + ((v.u >> 16) & 1u);
    return (unsigned short)(u >> 16);
}

#if __has_builtin(__builtin_amdgcn_global_load_lds)
#define HAVE_GLL 1
__device__ __forceinline__ void gload16(const void* g, void* l){
    __builtin_amdgcn_global_load_lds((const __attribute__((address_space(1))) void*)g,
                                     (__attribute__((address_space(3))) void*)l, 16, 0, 0);
}
#else
#define HAVE_GLL 0
#endif

// ============ inverse permutation ============
__global__ __launch_bounds__(256)
void k_inv(const int* __restrict__ hc, int* __restrict__ inv)
{
    int l = blockIdx.x*256 + threadIdx.x;
    inv[hc[l]] = l;
}

// ============ gather (transpose-tile) + LayerNorm1 ============
// block: (hw-tile of 32, nf, b). Coalesced reads of x/fx, contiguous row writes.
__global__ __launch_bounds__(256)
void k_gather_ln(const float* __restrict__ x, const float* __restrict__ fx,
                 const int* __restrict__ inv, const float* __restrict__ lw,
                 const float* __restrict__ lb, float* __restrict__ x_flat,
                 float* __restrict__ f_flat, unsigned short* __restrict__ normed)
{
    __shared__ float tile[DIMD*33];
    int hw0 = blockIdx.x * 32;
    int nf  = blockIdx.y;
    int b   = blockIdx.z;
    int t   = threadIdx.x;
    int hwi = t & 31, dr = t >> 5;          // 8 d-rows per iteration
    int w = t >> 6, lane = t & 63;          // wave mapping for row phase
    const float* xb = x  + ((size_t)(b*NFR+nf)*DIMD)*1024 + hw0;
    const float* fb = fx + ((size_t)(b*NFR+nf)*DIMD)*1024 + hw0;

    // -------- phase A: x --------
    for (int d0 = 0; d0 < DIMD; d0 += 8){
        int d = d0 + dr;
        tile[d*33 + hwi] = xb[(size_t)d*1024 + hwi];
    }
    __syncthreads();
    #pragma unroll
    for (int i = 0; i < 8; ++i){
        int r = w*8 + i;                     // hw index within tile
        int l = inv[nf*1024 + hw0 + r];
        size_t rowo = (size_t)(b*LSEQ + l)*DIMD;
        float v[6]; float s = 0.f, s2 = 0.f;
        #pragma unroll
        for (int c = 0; c < 6; ++c){
            float a = tile[(c*64 + lane)*33 + r];
            v[c] = a; s += a; s2 += a*a;
        }
        #pragma unroll
        for (int o = 1; o < 64; o <<= 1){ s += __shfl_xor(s, o); s2 += __shfl_xor(s2, o); }
        float mean = s * (1.f/DIMD);
        float var  = s2 * (1.f/DIMD) - mean*mean;
        float rs = rsqrtf(var + 1e-5f);
        #pragma unroll
        for (int c = 0; c < 6; ++c){
            int d = c*64 + lane;
            x_flat[rowo + d] = v[c];
            normed[rowo + d] = f2bf((v[c]-mean)*rs*lw[d] + lb[d]);
        }
    }
    __syncthreads();
    // -------- phase B: freq_x --------
    for (int d0 = 0; d0 < DIMD; d0 += 8){
        int d = d0 + dr;
        tile[d*33 + hwi] = fb[(size_t)d*1024 + hwi];
    }
    __syncthreads();
    #pragma unroll
    for (int i = 0; i < 8; ++i){
        int r = w*8 + i;
        int l = inv[nf*1024 + hw0 + r];
        size_t rowo = (size_t)(b*LSEQ + l)*DIMD;
        #pragma unroll
        for (int c = 0; c < 6; ++c)
            f_flat[rowo + c*64 + lane] = tile[(c*64 + lane)*33 + r];
    }
}

// ============ output scatter (transpose-tile): d_out[b,nf,d,hw] = outm[row(l),d] ============
__global__ __launch_bounds__(256)
void k_scatter(const float* __restrict__ outm, const int* __restrict__ inv,
               float* __restrict__ outp)
{
    __shared__ float tile[DIMD*33];
    int hw0 = blockIdx.x * 32;
    int nf  = blockIdx.y;
    int b   = blockIdx.z;
    int t   = threadIdx.x;
    int hwi = t & 31, dr = t >> 5;
    int w = t >> 6, lane = t & 63;
    #pragma unroll
    for (int i = 0; i < 8; ++i){
        int r = w*8 + i;
        int l = inv[nf*1024 + hw0 + r];
        const float* row = outm + (size_t)(b*LSEQ + l)*DIMD;
        #pragma unroll
        for (int c = 0; c < 6; ++c)
            tile[(c*64 + lane)*33 + r] = row[c*64 + lane];
    }
    __syncthreads();
    float* ob = outp + ((size_t)(b*NFR+nf)*DIMD)*1024 + hw0;
    for (int d0 = 0; d0 < DIMD; d0 += 8){
        int d = d0 + dr;
        ob[(size_t)d*1024 + hwi] = tile[d*33 + hwi];
    }
}

// ============ plain row LayerNorm (LN2), bf16 out ============
__global__ __launch_bounds__(128)
void k_ln(const float* __restrict__ in, const float* __restrict__ lw,
          const float* __restrict__ lb, unsigned short* __restrict__ out)
{
    size_t row = blockIdx.x;
    int t = threadIdx.x;
    float v[3]; float s = 0.f, s2 = 0.f;
    #pragma unroll
    for (int i = 0; i < 3; ++i){
        int d = t + i*128;
        float a = in[row*DIMD + d];
        v[i] = a; s += a; s2 += a*a;
    }
    #pragma unroll
    for (int o = 32; o > 0; o >>= 1){ s += __shfl_down(s, o); s2 += __shfl_down(s2, o); }
    __shared__ float sh[4];
    if ((t & 63) == 0){ sh[(t>>6)*2] = s; sh[(t>>6)*2+1] = s2; }
    __syncthreads();
    float S = sh[0] + sh[2], S2 = sh[1] + sh[3];
    float mean = S * (1.f/DIMD);
    float var  = S2 * (1.f/DIMD) - mean*mean;
    float r = rsqrtf(var + 1e-5f);
    #pragma unroll
    for (int i = 0; i < 3; ++i){
        int d = t + i*128;
        out[row*DIMD + d] = f2bf((v[i]-mean)*r*lw[d] + lb[d]);
    }
}

// ============ bf16 MFMA GEMM: C[M,N] = A[M,K](bf16) @ W[N,K](f32->bf16)^T ============
// EPI 0: plain f32 store.  EPI 1: +bias.  EPI 2: +bias +add, row store.
template<int EPI>
__global__ __launch_bounds__(256, 2)
void k_bgemm(const unsigned short* __restrict__ A, const float* __restrict__ Wf,
             const float* __restrict__ bias, const float* __restrict__ add,
             float* __restrict__ C, int N, int K)
{
    __shared__ unsigned short As[128*32];   // linear [128 rows][32 k]
    __shared__ unsigned short Bs[128*48];   // padded [128 rows][48] (32 used)
    int tid  = threadIdx.x;
    int wid  = tid >> 6, lane = tid & 63;
    int row0 = blockIdx.x * 128, col0 = blockIdx.y * 128;
    int wr = wid >> 1, wc = wid & 1;        // wave tile: 64x64
    int lr = lane & 15, lg = lane >> 4;

    f32x4 acc[4][4];
    #pragma unroll
    for (int m = 0; m < 4; ++m)
        #pragma unroll
        for (int n = 0; n < 4; ++n) acc[m][n] = (f32x4){0.f,0.f,0.f,0.f};

    // A staging geometry: slot byte s = wid*2048 + i*1024 + lane*16
    int sA0 = wid*2048 + lane*16;
    int rA0 = sA0 >> 6, kA0 = (sA0 & 63) >> 1;
    int sA1 = sA0 + 1024;
    int rA1 = sA1 >> 6, kA1 = (sA1 & 63) >> 1;
    const unsigned short* Ag0 = A + (size_t)(row0 + rA0)*K + kA0;
    const unsigned short* Ag1 = A + (size_t)(row0 + rA1)*K + kA1;
    // B staging: thread -> (n = tid>>1, kpart = (tid&1)*16)
    int bn = tid >> 1, bkp = (tid & 1) * 16;
    const float* Wg = Wf + (size_t)(col0 + bn)*K + bkp;

    const unsigned short* Ab = &As[(wr*64 + lr)*32 + lg*8];
    const unsigned short* Bb = &Bs[(wc*64 + lr)*48 + lg*8];
    unsigned short* Bw = &Bs[bn*48 + bkp];

    for (int k0 = 0; k0 < K; k0 += 32){
        if (k0) __syncthreads();
#if HAVE_GLL
        gload16(Ag0, (char*)As + wid*2048);
        gload16(Ag1, (char*)As + wid*2048 + 1024);
#else
        *(u16x8*)((char*)As + sA0) = *(const u16x8*)Ag0;
        *(u16x8*)((char*)As + sA1) = *(const u16x8*)Ag1;
#endif
        Ag0 += 32; Ag1 += 32;
        {
            float4 f0 = *(const float4*)(Wg+0);
            float4 f1 = *(const float4*)(Wg+4);
            float4 f2 = *(const float4*)(Wg+8);
            float4 f3 = *(const float4*)(Wg+12);
            Wg += 32;
            u16x8 p0, p1;
            p0[0]=f2bf(f0.x); p0[1]=f2bf(f0.y); p0[2]=f2bf(f0.z); p0[3]=f2bf(f0.w);
            p0[4]=f2bf(f1.x); p0[5]=f2bf(f1.y); p0[6]=f2bf(f1.z); p0[7]=f2bf(f1.w);
            p1[0]=f2bf(f2.x); p1[1]=f2bf(f2.y); p1[2]=f2bf(f2.z); p1[3]=f2bf(f2.w);
            p1[4]=f2bf(f3.x); p1[5]=f2bf(f3.y); p1[6]=f2bf(f3.z); p1[7]=f2bf(f3.w);
            *(u16x8*)(Bw)     = p0;
            *(u16x8*)(Bw + 8) = p1;
        }
        __syncthreads();
        bf16x8 af[4], bfr[4];
        #pragma unroll
        for (int m = 0; m < 4; ++m) af[m]  = *(const bf16x8*)(Ab + m*512);   // m*16*32
        #pragma unroll
        for (int n = 0; n < 4; ++n) bfr[n] = *(const bf16x8*)(Bb + n*768);   // n*16*48
        #pragma unroll
        for (int m = 0; m < 4; ++m)
            #pragma unroll
            for (int n = 0; n < 4; ++n)
                acc[m][n] = __builtin_amdgcn_mfma_f32_16x16x32_bf16(af[m], bfr[n], acc[m][n], 0, 0, 0);
    }

    // epilogue: D row = (lane>>4)*4 + r, col = lane&15 within each 16x16 frag
    #pragma unroll
    for (int m = 0; m < 4; ++m){
        #pragma unroll
        for (int r = 0; r < 4; ++r){
            int row = row0 + wr*64 + m*16 + lg*4 + r;
            #pragma unroll
            for (int n = 0; n < 4; ++n){
                int col = col0 + wc*64 + n*16 + lr;
                float v = acc[m][n][r];
                if (EPI >= 1) v += bias[col];
                if (EPI == 2) v += add[(size_t)row*N + col];
                C[(size_t)row*N + col] = v;
            }
        }
    }
}

// ============ causal + anti-causal depthwise conv over L, + silu ============
__global__ __launch_bounds__(256)
void k_conv(const float* __restrict__ xz, const float* __restrict__ cw,
            const float* __restrict__ cb, float* __restrict__ xcf, float* __restrict__ xcr)
{
    const int TL = 64;
    int b = blockIdx.y;
    int l0 = blockIdx.x * TL;
    __shared__ float sx[TL+6][DI];   // rows hold l0-3 .. l0+TL+2
    for (int idx = threadIdx.x; idx < (TL+6)*DI; idx += 256){
        int r = idx / DI, c = idx % DI;
        int l = l0 + r - 3;
        float v = 0.f;
        if (l >= 0 && l < LSEQ) v = xz[((size_t)b*LSEQ + l)*DIMD + c];
        sx[r][c] = v;
    }
    __syncthreads();
    for (int idx = threadIdx.x; idx < TL*DI; idx += 256){
        int r = idx / DI, c = idx % DI;
        float w0 = cw[c*4+0], w1 = cw[c*4+1], w2 = cw[c*4+2], w3 = cw[c*4+3];
        float bi = cb[c];
        size_t orow = ((size_t)b*LSEQ + l0 + r)*DI + c;
        float af = bi + sx[r][c]*w0 + sx[r+1][c]*w1 + sx[r+2][c]*w2 + sx[r+3][c]*w3;
        xcf[orow] = siluf(af);
        float ar = bi + sx[r+3][c]*w3 + sx[r+4][c]*w2 + sx[r+5][c]*w1 + sx[r+6][c]*w0;
        xcr[orow] = siluf(ar);
    }
}

// ============ dbl = xc @ xproj_w^T  (N=56, K=192) ============
__global__ __launch_bounds__(256)
void k_dbl(const float* __restrict__ xc, const float* __restrict__ xpw, float* __restrict__ dbl)
{
    __shared__ float sw[56*193];
    for (int i = threadIdx.x; i < 56*DI; i += 256){
        int n = i / DI, k = i % DI;
        sw[n*193 + k] = xpw[i];
    }
    __syncthreads();
    int n = threadIdx.x & 63;
    int ri = threadIdx.x >> 6;
    int row0 = blockIdx.x * 16;
    if (n < 56){
        for (int rp = 0; rp < 4; ++rp){
            int row = row0 + rp*4 + ri;
            const float* xr = xc + (size_t)row*DI;
            float acc = 0.f;
            #pragma unroll 8
            for (int k = 0; k < DI; ++k) acc += xr[k] * sw[n*193 + k];
            dbl[(size_t)row*56 + n] = acc;
        }
    }
}

// ============ dt = softplus(dbl[:, :24] @ dt_w^T + dt_b)  (N=192, K=24) ============
__global__ __launch_bounds__(192)
void k_dt(const float* __restrict__ dbl, const float* __restrict__ dtw,
          const float* __restrict__ dtb, float* __restrict__ dt)
{
    int row = blockIdx.x;
    int d = threadIdx.x;
    __shared__ float sd[24];
    if (d < 24) sd[d] = dbl[(size_t)row*56 + d];
    __syncthreads();
    float acc = dtb[d];
    #pragma unroll
    for (int r = 0; r < DRK; ++r) acc += sd[r] * dtw[d*DRK + r];
    dt[(size_t)row*DI + d] = softplusf(acc);
}

// ============ chunked selective scan ============
// p1: per-chunk composed (A = prod da, B = local scan from h=0)
__global__ __launch_bounds__(256)
void k_scan_p1(const float* __restrict__ dt_f, const float* __restrict__ dt_r,
               const float* __restrict__ dbl_f, const float* __restrict__ dbl_r,
               const float* __restrict__ xc_f, const float* __restrict__ xc_r,
               const float* __restrict__ A_log,
               float* __restrict__ CA, float* __restrict__ CB)
{
    int dir = blockIdx.z;
    int b   = blockIdx.y;
    int dg  = blockIdx.x >> 6;       // 0..11
    int ch  = blockIdx.x & (NCH-1);  // 0..63
    const float* dt  = dir ? dt_r  : dt_f;
    const float* dbl = dir ? dbl_r : dbl_f;
    const float* xc  = dir ? xc_r  : xc_f;
    int d0 = dg*16;
    int tid = threadIdx.x;
    int s = tid & 15, di = tid >> 4;
    int d = d0 + di;
    float A2 = -expf(A_log[d*DST + s]) * 1.44269504f;
    float hA = 1.f, hB = 0.f;
    __shared__ float sdt[16][16], sxv[16][16], sB[16][16];
    int r = tid >> 4, cix = tid & 15;
    for (int sub = 0; sub < CL/16; ++sub){
        __syncthreads();
        int lidx = ch*CL + sub*16 + r;
        int lld = dir ? (LSEQ-1-lidx) : lidx;
        size_t rowbl = (size_t)b*LSEQ + lld;
        sdt[r][cix] = dt[rowbl*DI + d0 + cix];
        sxv[r][cix] = xc[rowbl*DI + d0 + cix];
        sB[r][cix]  = dbl[rowbl*56 + 24 + cix];
        __syncthreads();
        #pragma unroll
        for (int j = 0; j < 16; ++j){
            float dtv = sdt[j][di];
            float da  = exp2f(dtv * A2);
            float db  = dtv * sB[j][s] * sxv[j][di];
            hA *= da;
            hB = da*hB + db;
        }
    }
    size_t o = ((((size_t)dir*B_N + b)*12 + dg)*NCH + ch)*256 + tid;
    CA[o] = hA; CB[o] = hB;
}

// p2: sequential combine over chunk summaries -> incoming state per chunk
__global__ __launch_bounds__(256)
void k_scan_p2(const float* __restrict__ CA, const float* __restrict__ CB,
               float* __restrict__ CH)
{
    int dir = blockIdx.z, b = blockIdx.y, dg = blockIdx.x;
    int tid = threadIdx.x;
    size_t base = ((((size_t)dir*B_N + b)*12 + dg)*NCH)*256 + tid;
    float h = 0.f;
    for (int c = 0; c < NCH; ++c){
        size_t o = base + (size_t)c*256;
        CH[o] = h;
        h = CA[o]*h + CB[o];
    }
}

// p3: rescan from h_in, compute y, gate, write g (bf16)
__global__ __launch_bounds__(256)
void k_scan_p3(const float* __restrict__ dt_f, const float* __restrict__ dt_r,
               const float* __restrict__ dbl_f, const float* __restrict__ dbl_r,
               const float* __restrict__ xc_f, const float* __restrict__ xc_r,
               const float* __restrict__ xz, const float* __restrict__ A_log,
               const float* __restrict__ Dp, const float* __restrict__ CH,
               unsigned short* __restrict__ g_f, unsigned short* __restrict__ g_r)
{
    int dir = blockIdx.z;
    int b   = blockIdx.y;
    int dg  = blockIdx.x >> 6;
    int ch  = blockIdx.x & (NCH-1);
    const float* dt  = dir ? dt_r  : dt_f;
    const float* dbl = dir ? dbl_r : dbl_f;
    const float* xc  = dir ? xc_r  : xc_f;
    unsigned short* g = dir ? g_r : g_f;
    int d0 = dg*16;
    int tid = threadIdx.x;
    int s = tid & 15, di = tid >> 4;
    int d = d0 + di;
    float A2  = -expf(A_log[d*DST + s]) * 1.44269504f;
    float Dpd = Dp[d];
    float h = CH[((((size_t)dir*B_N + b)*12 + dg)*NCH + ch)*256 + tid];
    __shared__ float sdt[16][16], sxv[16][16], szv[16][16], sB[16][16], sC[16][16];
    int r = tid >> 4, cix = tid & 15;
    for (int sub = 0; sub < CL/16; ++sub){
        __syncthreads();
        int lidx = ch*CL + sub*16 + r;
        int lld = dir ? (LSEQ-1-lidx) : lidx;
        size_t rowbl = (size_t)b*LSEQ + lld;
        sdt[r][cix] = dt[rowbl*DI + d0 + cix];
        sxv[r][cix] = xc[rowbl*DI + d0 + cix];
        szv[r][cix] = xz[rowbl*DIMD + DI + d0 + cix];
        sB[r][cix]  = dbl[rowbl*56 + 24 + cix];
        sC[r][cix]  = dbl[rowbl*56 + 40 + cix];
        __syncthreads();
        #pragma unroll 4
        for (int j = 0; j < 16; ++j){
            float dtv = sdt[j][di];
            float xv  = sxv[j][di];
            float da  = exp2f(dtv * A2);
            float db  = dtv * sB[j][s] * xv;
            h = da*h + db;
            float yc = h * sC[j][s];
            yc += __shfl_xor(yc, 8);
            yc += __shfl_xor(yc, 4);
            yc += __shfl_xor(yc, 2);
            yc += __shfl_xor(yc, 1);
            if (s == 0){
                float zv = szv[j][di];
                int lidxj = ch*CL + sub*16 + j;
                int lw = dir ? (LSEQ-1-lidxj) : lidxj;
                g[((size_t)b*LSEQ + lw)*DI + d] = f2bf((yc + Dpd*xv) * siluf(zv));
            }
        }
    }
}

// ============ pooled partial sums over L (for SSA) — high-parallelism ============
__global__ __launch_bounds__(384)
void k_pool(const float* __restrict__ m_f, const float* __restrict__ m_r,
            const float* __restrict__ f_flat, float* __restrict__ partial)
{
    int bt = blockIdx.x;      // b*3 + t
    int sl = blockIdx.y;      // PSL slices of LSEQ/PSL rows
    int b = bt / 3, t = bt % 3;
    const float* src = (t == 0) ? m_f : (t == 1) ? m_r : f_flat;
    src += (size_t)b*LSEQ*DIMD + (size_t)sl*(LSEQ/PSL)*DIMD;
    int d = threadIdx.x;
    float sum = 0.f;
    #pragma unroll 8
    for (int l = 0; l < LSEQ/PSL; ++l) sum += src[(size_t)l*DIMD + d];
    partial[((size_t)bt*PSL + sl)*DIMD + d] = sum;
}

// ============ SSA attention weights: softmax over t ============
__global__ __launch_bounds__(384)
void k_ssa(const float* __restrict__ partial, const float* __restrict__ ssaw,
           float* __restrict__ aw)
{
    int b = blockIdx.x;
    int d = threadIdx.x;
    float pooled[3];
    #pragma unroll
    for (int t = 0; t < 3; ++t){
        float sum = 0.f;
        for (int sl = 0; sl < PSL; ++sl) sum += partial[((size_t)(b*3+t)*PSL + sl)*DIMD + d];
        pooled[t] = sum * (1.f/LSEQ);
    }
    float wv[3];
    #pragma unroll
    for (int t = 0; t < 3; ++t)
        wv[t] = pooled[0]*ssaw[d*9 + t*3 + 0] + pooled[1]*ssaw[d*9 + t*3 + 1] + pooled[2]*ssaw[d*9 + t*3 + 2];
    float mx = fmaxf(wv[0], fmaxf(wv[1], wv[2]));
    float e0 = expf(wv[0]-mx), e1 = expf(wv[1]-mx), e2 = expf(wv[2]-mx);
    float inv_ = 1.f / (e0+e1+e2);
    aw[(size_t)(b*3+0)*DIMD + d] = e0*inv_;
    aw[(size_t)(b*3+1)*DIMD + d] = e1*inv_;
    aw[(size_t)(b*3+2)*DIMD + d] = e2*inv_;
}

// ============ xm = x_flat + sum_t aw[t]*seq_t ============
__global__ __launch_bounds__(256)
void k_xm(const float* __restrict__ x_flat, const float* __restrict__ m_f,
          const float* __restrict__ m_r, const float* __restrict__ f_flat,
          const float* __restrict__ aw, float* __restrict__ xm)
{
    size_t idx = (size_t)blockIdx.x*256 + threadIdx.x;
    int d = (int)(idx % DIMD);
    size_t row = idx / DIMD;
    int b = (int)(row >> 13);
    float a0 = aw[(size_t)(b*3+0)*DIMD + d];
    float a1 = aw[(size_t)(b*3+1)*DIMD + d];
    float a2 = aw[(size_t)(b*3+2)*DIMD + d];
    xm[idx] = x_flat[idx] + a0*m_f[idx] + a1*m_r[idx] + a2*f_flat[idx];
}

// ============ depthwise 3x3x3 conv over (NF,H,W) + bias + exact GELU (bf16 out) ============
__global__ __launch_bounds__(256)
void k_dwconv(const float* __restrict__ h1, const float* __restrict__ dww,
              const float* __restrict__ dwb, unsigned short* __restrict__ h2)
{
    int c = blockIdx.x*256 + threadIdx.x;
    int h = blockIdx.y;
    int bnf = blockIdx.z; int b = bnf >> 3, nf = bnf & 7;
    float wt[27];
    #pragma unroll
    for (int i = 0; i < 27; ++i) wt[i] = dww[(size_t)c*27 + i];
    float bias = dwb[c];
    bool nfok[3], hok[3];
    #pragma unroll
    for (int dd = 0; dd < 3; ++dd){
        nfok[dd] = (nf+dd-1) >= 0 && (nf+dd-1) < NFR;
        hok[dd]  = (h+dd-1)  >= 0 && (h+dd-1)  < HH;
    }
    const float* base = h1 + (size_t)b*LSEQ*HID + c;
    float win[3][3][3];
    #pragma unroll
    for (int dn = 0; dn < 3; ++dn)
        #pragma unroll
        for (int dh = 0; dh < 3; ++dh){
            bool ok = nfok[dn] && hok[dh];
            size_t rb = ((size_t)(nf+dn-1)*1024 + (size_t)(h+dh-1)*32);
            win[dn][dh][0] = 0.f;
            win[dn][dh][1] = ok ? base[(rb + 0)*HID] : 0.f;
            win[dn][dh][2] = ok ? base[(rb + 1)*HID] : 0.f;
        }
    for (int xw = 0; xw < WW; ++xw){
        float acc = bias;
        #pragma unroll
        for (int dn = 0; dn < 3; ++dn)
            #pragma unroll
            for (int dh = 0; dh < 3; ++dh)
                #pragma unroll
                for (int dw = 0; dw < 3; ++dw)
                    acc += win[dn][dh][dw] * wt[dn*9 + dh*3 + dw];
        h2[((size_t)b*LSEQ + nf*1024 + h*32 + xw)*HID + c] = f2bf(geluf(acc));
        int wn = xw + 2;
        #pragma unroll
        for (int dn = 0; dn < 3; ++dn)
            #pragma unroll
            for (int dh = 0; dh < 3; ++dh){
                win[dn][dh][0] = win[dn][dh][1];
                win[dn][dh][1] = win[dn][dh][2];
                bool ok = (wn < WW) && nfok[dn] && hok[dh];
                size_t rb = ((size_t)(nf+dn-1)*1024 + (size_t)(h+dh-1)*32);
                win[dn][dh][2] = ok ? base[(rb + wn)*HID] : 0.f;
            }
    }
}

// ================================================================
extern "C" void kernel_launch(void* const* d_in, const int* in_sizes, int n_in,
                              void* d_out, int out_size, void* d_ws, size_t ws_size,
                              hipStream_t stream)
{
    const float* x     = (const float*)d_in[0];
    const float* fx    = (const float*)d_in[1];
    const int*   hc    = (const int*)  d_in[2];
    const float* ln1w  = (const float*)d_in[3];
    const float* ln1b  = (const float*)d_in[4];
    const float* inpw  = (const float*)d_in[5];
    const float* convw = (const float*)d_in[6];
    const float* convb = (const float*)d_in[7];
    const float* xpw   = (const float*)d_in[8];
    const float* dtw   = (const float*)d_in[9];
    const float* dtb   = (const float*)d_in[10];
    const float* alog  = (const float*)d_in[11];
    const float* dp    = (const float*)d_in[12];
    const float* outpw = (const float*)d_in[13];
    const float* ssaw  = (const float*)d_in[14];
    const float* ln2w  = (const float*)d_in[15];
    const float* ln2b  = (const float*)d_in[16];
    const float* fc1w  = (const float*)d_in[17];
    const float* fc1b  = (const float*)d_in[18];
    const float* dww   = (const float*)d_in[19];
    const float* dwb   = (const float*)d_in[20];
    const float* fc2w  = (const float*)d_in[21];
    const float* fc2b  = (const float*)d_in[22];

    float* ws = (float*)d_ws;
    float* x_flat = ws + OFF_XFLAT;
    float* f_flat = ws + OFF_FFLAT;
    float* xz     = ws + OFF_XZ;
    float* xc_f   = ws + OFF_XCF;
    float* xc_r   = ws + OFF_XCR;
    float* dbl_f  = ws + OFF_DBLF;
    float* dbl_r  = ws + OFF_DBLR;
    float* dt_f   = ws + OFF_DTF;
    float* dt_r   = ws + OFF_DTR;
    float* m_f    = ws + OFF_MF;
    float* m_r    = ws + OFF_MR_;
    float* h1     = ws + OFF_H1;
    float* xm     = ws + OFF_XM;
    float* part   = ws + OFF_PART;
    float* aw     = ws + OFF_AW;
    float* cA     = ws + OFF_CA;
    float* cB     = ws + OFF_CB;
    float* cH     = ws + OFF_CHS;
    float* outm   = ws + OFF_NORM;   // f32, aliases normed (dead after fc1)
    int*   inv    = (int*)(ws + OFF_INV);
    unsigned short* nrm_bf = (unsigned short*)(ws + OFF_NORM);
    unsigned short* gf_bf  = (unsigned short*)(ws + OFF_GF);
    unsigned short* gr_bf  = (unsigned short*)(ws + OFF_GR);
    unsigned short* h2_bf  = (unsigned short*)(ws + OFF_H2);
    float* outp   = (float*)d_out;

    // 0. inverse permutation
    k_inv<<<LSEQ/256, 256, 0, stream>>>(hc, inv);
    // 1. gather + LN1 (bf16 normed) — transpose-tile, coalesced
    k_gather_ln<<<dim3(32, NFR, B_N), 256, 0, stream>>>(x, fx, inv, ln1w, ln1b, x_flat, f_flat, nrm_bf);
    // 2. in_proj (MFMA bf16, shared by fwd & rev)
    k_bgemm<0><<<dim3(128,3), 256, 0, stream>>>(nrm_bf, inpw, nullptr, nullptr, xz, DIMD, DIMD);
    // 3. causal/anti-causal depthwise conv + silu
    k_conv<<<dim3(LSEQ/64, B_N), 256, 0, stream>>>(xz, convw, convb, xc_f, xc_r);
    // 4. x-proj (dbl = [dt_raw, B, C])
    k_dbl<<<MR/16, 256, 0, stream>>>(xc_f, xpw, dbl_f);
    k_dbl<<<MR/16, 256, 0, stream>>>(xc_r, xpw, dbl_r);
    // 5. dt projection + softplus
    k_dt<<<MR, 192, 0, stream>>>(dbl_f, dtw, dtb, dt_f);
    k_dt<<<MR, 192, 0, stream>>>(dbl_r, dtw, dtb, dt_r);
    // 6. chunked selective scans (both dirs; nrm_bf dead here)
    k_scan_p1<<<dim3(12*NCH, B_N, 2), 256, 0, stream>>>(dt_f, dt_r, dbl_f, dbl_r, xc_f, xc_r, alog, cA, cB);
    k_scan_p2<<<dim3(12, B_N, 2), 256, 0, stream>>>(cA, cB, cH);
    k_scan_p3<<<dim3(12*NCH, B_N, 2), 256, 0, stream>>>(dt_f, dt_r, dbl_f, dbl_r, xc_f, xc_r, xz, alog, dp, cH, gf_bf, gr_bf);
    // 7. out_proj (MFMA bf16)
    k_bgemm<0><<<dim3(128,3), 256, 0, stream>>>(gf_bf, outpw, nullptr, nullptr, m_f, DIMD, DI);
    k_bgemm<0><<<dim3(128,3), 256, 0, stream>>>(gr_bf, outpw, nullptr, nullptr, m_r, DIMD, DI);
    // 8. SSA
    k_pool<<<dim3(6,PSL), 384, 0, stream>>>(m_f, m_r, f_flat, part);
    k_ssa<<<B_N, 384, 0, stream>>>(part, ssaw, aw);
    k_xm<<<(unsigned)(SZ_BLD/256), 256, 0, stream>>>(x_flat, m_f, m_r, f_flat, aw, xm);
    // 9. MLP
    k_ln<<<MR, 128, 0, stream>>>(xm, ln2w, ln2b, nrm_bf);
    k_bgemm<1><<<dim3(128,12), 256, 0, stream>>>(nrm_bf, fc1w, fc1b, nullptr, h1, HID, DIMD);
    k_dwconv<<<dim3(6,32,16), 256, 0, stream>>>(h1, dww, dwb, h2_bf);
    // 10. fc2 + bias + residual -> outm (rows), then transpose-scatter to d_out
    k_bgemm<2><<<dim3(128,3), 256, 0, stream>>>(h2_bf, fc2w, fc2b, xm, outm, DIMD, HID);
    k_scatter<<<dim3(32, NFR, B_N), 256, 0, stream>>>(outm, inv, outp);
}